// Round 3
// baseline (367323.706 us; speedup 1.0000x reference)
//
#include <hip/hip_runtime.h>
#include <cmath>

#define NN 10000
#define EE 200000
#define BB 64
#define NCK 50
#define NCAND 5
#define TOKS 38
#define TITLE 30
#define GDIM 300
#define HH 20
#define DHD 20
#define DD 400
#define PP 200

__device__ __forceinline__ float bf2f(unsigned short u) {
    return __uint_as_float(((unsigned int)u) << 16);
}
__device__ __forceinline__ unsigned short f2bf(float f) {
    unsigned int u = __float_as_uint(f);
    u += 0x7fffu + ((u >> 16) & 1u);
    return (unsigned short)(u >> 16);
}

// ---------------------------------------------------------------------------
// K1: fused news encoder. One block (256 thr) per news item.
// ---------------------------------------------------------------------------
struct __align__(16) NewsP1 {
    unsigned short embT[GDIM][40];   // [g][t] bf16 transposed; t in [30,40) zeroed
    unsigned short W3[30][64];       // per-head wq|wk|wv slice chunk, c in [60,64) zero
    float qkv[3][TITLE][DHD];
    float sc[TITLE][32];
};
struct __align__(16) NewsP2 {
    float wp_t[16][PP];
    float outf[16][36];              // transposed out tile [dd][t]
    float qpl[PP];
    float part[25][32];
};
struct __align__(16) NewsSmem {
    union { NewsP1 p1; NewsP2 p2; } u;  // 38880 B
    unsigned short outb[TITLE][408];     // 24480 B (bf16 attention output)
    int tok[32];
    float alpha[32];
};  // total ~63.6 KB

__global__ __launch_bounds__(256) void news_enc(
    const int* __restrict__ tokens, int tok_stride,
    const float* __restrict__ glove,
    const float* __restrict__ wq, const float* __restrict__ wk,
    const float* __restrict__ wv,
    const float* __restrict__ wp, const float* __restrict__ qp,
    float* __restrict__ out_enc)
{
    __shared__ NewsSmem sm;
    const int tid = threadIdx.x;
    const int item = blockIdx.x;

    if (tid < TITLE) sm.tok[tid] = tokens[(size_t)item * tok_stride + tid];
    __syncthreads();

    // gather glove rows -> embT (bf16, transposed)
    for (int i = tid; i < TITLE * 75; i += 256) {
        int t = i / 75, g4 = i % 75;
        const float4 v = *(const float4*)&glove[(size_t)sm.tok[t] * GDIM + g4 * 4];
        sm.u.p1.embT[g4*4+0][t] = f2bf(v.x);
        sm.u.p1.embT[g4*4+1][t] = f2bf(v.y);
        sm.u.p1.embT[g4*4+2][t] = f2bf(v.z);
        sm.u.p1.embT[g4*4+3][t] = f2bf(v.w);
    }
    for (int i = tid; i < GDIM * 10; i += 256) {   // zero t = 30..39
        int g = i / 10, t = TITLE + i % 10;
        sm.u.p1.embT[g][t] = 0;
    }

    const int col = tid & 63;          // 0..63 (cols 60..63 idle)
    const int tg  = tid >> 6;          // wave id 0..3
    const int t0  = tg * 8;
    const int nt  = (t0 + 8 <= TITLE) ? 8 : (TITLE - t0);   // 8,8,8,6

    for (int h = 0; h < HH; ++h) {
        float acc[8] = {0,0,0,0,0,0,0,0};
        for (int gc = 0; gc < 10; ++gc) {
            for (int i = tid; i < 30*64; i += 256) {
                int gg = i >> 6, c = i & 63;
                unsigned short val = 0;
                if (c < 60) {
                    int m = c / 20, cc = c % 20;
                    const float* W = (m == 0) ? wq : ((m == 1) ? wk : wv);
                    val = f2bf(W[(size_t)(gc*30+gg)*DD + h*DHD + cc]);
                }
                sm.u.p1.W3[gg][c] = val;
            }
            __syncthreads();
            for (int gg = 0; gg < 30; ++gg) {
                const uint4 pk = *(const uint4*)&sm.u.p1.embT[gc*30+gg][t0];
                float e0 = __uint_as_float(pk.x << 16);
                float e1 = __uint_as_float(pk.x & 0xffff0000u);
                float e2 = __uint_as_float(pk.y << 16);
                float e3 = __uint_as_float(pk.y & 0xffff0000u);
                float e4 = __uint_as_float(pk.z << 16);
                float e5 = __uint_as_float(pk.z & 0xffff0000u);
                float e6 = __uint_as_float(pk.w << 16);
                float e7 = __uint_as_float(pk.w & 0xffff0000u);
                float w = bf2f(sm.u.p1.W3[gg][col]);
                acc[0] += e0*w; acc[1] += e1*w; acc[2] += e2*w; acc[3] += e3*w;
                acc[4] += e4*w; acc[5] += e5*w; acc[6] += e6*w; acc[7] += e7*w;
            }
            __syncthreads();
        }
        if (col < 60) {
            int m = col / 20, cc = col % 20;
            // STATIC unroll with guard: keeps acc[] in VGPRs (runtime bound
            // nt previously forced acc[] into scratch -> 300+ GB spill traffic)
            #pragma unroll
            for (int j = 0; j < 8; ++j)
                if (j < nt) sm.u.p1.qkv[m][t0+j][cc] = acc[j];
        }
        __syncthreads();
        // scores = q k^T * 1/sqrt(20)
        for (int i = tid; i < TITLE*TITLE; i += 256) {
            int t = i / TITLE, k2 = i % TITLE;
            float s = 0.f;
            #pragma unroll
            for (int d4 = 0; d4 < 5; ++d4) {
                const float4 qa = *(const float4*)&sm.u.p1.qkv[0][t][d4*4];
                const float4 kb = *(const float4*)&sm.u.p1.qkv[1][k2][d4*4];
                s += qa.x*kb.x + qa.y*kb.y + qa.z*kb.z + qa.w*kb.w;
            }
            sm.u.p1.sc[t][k2] = s * 0.2236067977f;
        }
        __syncthreads();
        if (tid < TITLE) {
            float mx = -1e30f;
            for (int k2 = 0; k2 < TITLE; ++k2) mx = fmaxf(mx, sm.u.p1.sc[tid][k2]);
            float ssum = 0.f;
            for (int k2 = 0; k2 < TITLE; ++k2) {
                float e = __expf(sm.u.p1.sc[tid][k2] - mx);
                sm.u.p1.sc[tid][k2] = e; ssum += e;
            }
            float inv = 1.f / ssum;
            for (int k2 = 0; k2 < TITLE; ++k2) sm.u.p1.sc[tid][k2] *= inv;
        }
        __syncthreads();
        for (int i = tid; i < TITLE*DHD; i += 256) {
            int t = i / DHD, d = i % DHD;
            float o = 0.f;
            for (int k2 = 0; k2 < TITLE; ++k2)
                o += sm.u.p1.sc[t][k2] * sm.u.p1.qkv[2][k2][d];
            sm.outb[t][h*DHD + d] = f2bf(o);
        }
        __syncthreads();
    }

    // ---- token attention pooling ----
    for (int i = tid; i < PP; i += 256) sm.u.p2.qpl[i] = qp[i];
    float sreg[4][8];
    #pragma unroll
    for (int i = 0; i < 4; ++i)
        #pragma unroll
        for (int j = 0; j < 8; ++j) sreg[i][j] = 0.f;
    const int tb = tid & 7, pb = tid >> 3;   // valid for tid<200
    for (int dc = 0; dc < 25; ++dc) {
        for (int i = tid; i < 16*PP; i += 256) {
            int dd = i / PP, p = i % PP;
            sm.u.p2.wp_t[dd][p] = wp[(size_t)(dc*16+dd)*PP + p];
        }
        for (int i = tid; i < 16*36; i += 256) {
            int dd = i / 36, t = i % 36;
            sm.u.p2.outf[dd][t] = (t < TITLE) ? bf2f(sm.outb[t][dc*16+dd]) : 0.f;
        }
        __syncthreads();
        if (tid < 200) {
            for (int dd = 0; dd < 16; ++dd) {
                const float4 ev = *(const float4*)&sm.u.p2.outf[dd][tb*4];
                const float4 w0 = *(const float4*)&sm.u.p2.wp_t[dd][pb*8];
                const float4 w1 = *(const float4*)&sm.u.p2.wp_t[dd][pb*8+4];
                float evv[4] = {ev.x, ev.y, ev.z, ev.w};
                float wvv[8] = {w0.x,w0.y,w0.z,w0.w,w1.x,w1.y,w1.z,w1.w};
                #pragma unroll
                for (int i2 = 0; i2 < 4; ++i2)
                    #pragma unroll
                    for (int j = 0; j < 8; ++j) sreg[i2][j] += evv[i2]*wvv[j];
            }
        }
        __syncthreads();
    }
    if (tid < 200) {
        #pragma unroll
        for (int i2 = 0; i2 < 4; ++i2) {
            float part = 0.f;
            #pragma unroll
            for (int j = 0; j < 8; ++j)
                part += tanhf(sreg[i2][j]) * sm.u.p2.qpl[pb*8+j];
            sm.u.p2.part[pb][tb*4+i2] = part;
        }
    }
    __syncthreads();
    if (tid < TITLE) {
        float s = 0.f;
        for (int p2 = 0; p2 < 25; ++p2) s += sm.u.p2.part[p2][tid];
        sm.alpha[tid] = s;
    }
    __syncthreads();
    if (tid == 0) {
        float mx = -1e30f;
        for (int t = 0; t < TITLE; ++t) mx = fmaxf(mx, sm.alpha[t]);
        float ssum = 0.f;
        for (int t = 0; t < TITLE; ++t) { float e = __expf(sm.alpha[t]-mx); sm.alpha[t] = e; ssum += e; }
        float inv = 1.f/ssum;
        for (int t = 0; t < TITLE; ++t) sm.alpha[t] *= inv;
    }
    __syncthreads();
    for (int d = tid; d < DD; d += 256) {
        float a = 0.f;
        for (int t = 0; t < TITLE; ++t) a += sm.alpha[t] * bf2f(sm.outb[t][d]);
        out_enc[(size_t)item*DD + d] = a;
    }
}

// ---------------------------------------------------------------------------
// K2a: m = h @ W  ([N,400]@[400,400]); 8 rows per block
// ---------------------------------------------------------------------------
__global__ __launch_bounds__(256) void mm_nodes(
    const float* __restrict__ A, const float* __restrict__ W, float* __restrict__ Mo)
{
    __shared__ float a[8][DD];
    const int r0 = blockIdx.x * 8, tid = threadIdx.x;
    for (int i = tid; i < 8*DD; i += 256)
        a[i/DD][i%DD] = A[(size_t)(r0 + i/DD)*DD + i%DD];
    __syncthreads();
    for (int d = tid; d < DD; d += 256) {
        float acc[8] = {0,0,0,0,0,0,0,0};
        for (int k4 = 0; k4 < 100; ++k4) {
            float w0 = W[(size_t)(k4*4+0)*DD + d];
            float w1 = W[(size_t)(k4*4+1)*DD + d];
            float w2 = W[(size_t)(k4*4+2)*DD + d];
            float w3 = W[(size_t)(k4*4+3)*DD + d];
            #pragma unroll
            for (int r = 0; r < 8; ++r) {
                const float4 av = *(const float4*)&a[r][k4*4];
                acc[r] += av.x*w0 + av.y*w1 + av.z*w2 + av.w*w3;
            }
        }
        for (int r = 0; r < 8; ++r) Mo[(size_t)(r0+r)*DD + d] = acc[r];
    }
}

// ---------------------------------------------------------------------------
// CSR build: count -> exclusive scan -> cursor scatter
// ---------------------------------------------------------------------------
__global__ __launch_bounds__(256) void count_edges(
    const int* __restrict__ ei, int* __restrict__ cnt)
{
    int e = blockIdx.x * 256 + threadIdx.x;
    if (e < EE) atomicAdd(&cnt[ei[EE + e]], 1);
}

__global__ __launch_bounds__(256) void build_offsets(
    const int* __restrict__ cnt, int* __restrict__ off, int* __restrict__ cursor)
{
    __shared__ int csum[256];
    const int tid = threadIdx.x;
    const int chunk = (NN + 255) / 256;   // 40
    int s = 0;
    for (int i = 0; i < chunk; ++i) {
        int idx = tid * chunk + i;
        if (idx < NN) s += cnt[idx];
    }
    csum[tid] = s;
    __syncthreads();
    if (tid == 0) {
        int run = 0;
        for (int i = 0; i < 256; ++i) { int c = csum[i]; csum[i] = run; run += c; }
    }
    __syncthreads();
    int run = csum[tid];
    for (int i = 0; i < chunk; ++i) {
        int idx = tid * chunk + i;
        if (idx < NN) {
            off[idx] = run; cursor[idx] = run;
            run += cnt[idx];
        }
    }
}

__global__ __launch_bounds__(256) void fill_csr(
    const int* __restrict__ ei, int* __restrict__ cursor, int* __restrict__ srclist)
{
    int e = blockIdx.x * 256 + threadIdx.x;
    if (e < EE) {
        int d = ei[EE + e];
        int pos = atomicAdd(&cursor[d], 1);
        srclist[pos] = ei[e];
    }
}

// ---------------------------------------------------------------------------
// K2b: agg[node] = sum over incoming edges of m[src]  (no float atomics)
// ---------------------------------------------------------------------------
__global__ __launch_bounds__(256) void gather_agg(
    const float* __restrict__ m, const int* __restrict__ off,
    const int* __restrict__ cnt, const int* __restrict__ srclist,
    float* __restrict__ agg)
{
    __shared__ int sl[128];
    const int node = blockIdx.x, tid = threadIdx.x;
    const int o0 = off[node], deg = cnt[node];
    float acc0 = 0.f, acc1 = 0.f;
    const int d0 = tid, d1 = tid + 256;          // d1 valid if < 400
    for (int j0 = 0; j0 < deg; j0 += 128) {
        if (tid < 128 && j0 + tid < deg) sl[tid] = srclist[o0 + j0 + tid];
        __syncthreads();
        const int jn = (deg - j0 < 128) ? (deg - j0) : 128;
        for (int j = 0; j < jn; ++j) {
            const float* mr = &m[(size_t)sl[j] * DD];
            acc0 += mr[d0];
            if (d1 < DD) acc1 += mr[d1];
        }
        __syncthreads();
    }
    agg[(size_t)node * DD + d0] = acc0;
    if (d1 < DD) agg[(size_t)node * DD + d1] = acc1;
}

// ---------------------------------------------------------------------------
// K2c: fused GRU cell; 8 rows per block. Safe in-place (hin may == hout).
// ---------------------------------------------------------------------------
__global__ __launch_bounds__(256) void gru_step(
    const float* __restrict__ agg, const float* __restrict__ hin,
    const float* __restrict__ wih, const float* __restrict__ whh,
    const float* __restrict__ bih, const float* __restrict__ bhh,
    float* __restrict__ hout)
{
    __shared__ float al[8][DD], hl[8][DD];
    const int r0 = blockIdx.x * 8, tid = threadIdx.x;
    for (int i = tid; i < 8*DD; i += 256) {
        int r = i/DD, k = i%DD;
        al[r][k] = agg[(size_t)(r0+r)*DD + k];
        hl[r][k] = hin[(size_t)(r0+r)*DD + k];
    }
    __syncthreads();
    for (int d = tid; d < DD; d += 256) {
        float air[8]={0,0,0,0,0,0,0,0}, aiz[8]={0,0,0,0,0,0,0,0}, ain[8]={0,0,0,0,0,0,0,0};
        float ahr[8]={0,0,0,0,0,0,0,0}, ahz[8]={0,0,0,0,0,0,0,0}, ahn[8]={0,0,0,0,0,0,0,0};
        for (int k = 0; k < DD; ++k) {
            const float* wi = &wih[(size_t)k*1200 + d];
            float wir = wi[0], wiz = wi[400], win = wi[800];
            const float* wh = &whh[(size_t)k*1200 + d];
            float whr = wh[0], whz = wh[400], whn = wh[800];
            #pragma unroll
            for (int r = 0; r < 8; ++r) {
                float a = al[r][k], hh = hl[r][k];
                air[r] += a*wir; aiz[r] += a*wiz; ain[r] += a*win;
                ahr[r] += hh*whr; ahz[r] += hh*whz; ahn[r] += hh*whn;
            }
        }
        float bir = bih[d], biz = bih[d+400], bin = bih[d+800];
        float bhr = bhh[d], bhz = bhh[d+400], bhn = bhh[d+800];
        #pragma unroll
        for (int r = 0; r < 8; ++r) {
            float rg = 1.f/(1.f + __expf(-(air[r]+bir + ahr[r]+bhr)));
            float zg = 1.f/(1.f + __expf(-(aiz[r]+biz + ahz[r]+bhz)));
            float ng = tanhf(ain[r]+bin + rg*(ahn[r]+bhn));
            hout[(size_t)(r0+r)*DD + d] = (1.f-zg)*ng + zg*hl[r][d];
        }
    }
}

// ---------------------------------------------------------------------------
// K3a: clicked_total = concat(x_enc[midx], h[midx])*mask @ w_click + b_click
// ---------------------------------------------------------------------------
__global__ __launch_bounds__(256) void clicked_mm(
    const int* __restrict__ map, const float* __restrict__ xe,
    const float* __restrict__ hg, const float* __restrict__ wc,
    const float* __restrict__ bc, float* __restrict__ ct)
{
    __shared__ float a[8][2*DD];
    const int r0 = blockIdx.x * 8, tid = threadIdx.x;
    for (int i = tid; i < 8*2*DD; i += 256) {
        int r = i/(2*DD), k = i%(2*DD);
        int mi = map[r0 + r];
        float v = 0.f;
        if (mi >= 0) v = (k < DD) ? xe[(size_t)mi*DD + k] : hg[(size_t)mi*DD + (k-DD)];
        a[r][k] = v;
    }
    __syncthreads();
    for (int d = tid; d < DD; d += 256) {
        float acc[8] = {0,0,0,0,0,0,0,0};
        for (int k = 0; k < 2*DD; ++k) {
            float w = wc[(size_t)k*DD + d];
            #pragma unroll
            for (int r = 0; r < 8; ++r) acc[r] += a[r][k]*w;
        }
        float bb = bc[d];
        for (int r = 0; r < 8; ++r) ct[(size_t)(r0+r)*DD + d] = acc[r] + bb;
    }
}

// ---------------------------------------------------------------------------
// K3b: uq/uk/uv = ct @ u_wq/u_wk/u_wv
// ---------------------------------------------------------------------------
__global__ __launch_bounds__(256) void user_qkv(
    const float* __restrict__ ct,
    const float* __restrict__ wq, const float* __restrict__ wk, const float* __restrict__ wv,
    float* __restrict__ uq, float* __restrict__ uk, float* __restrict__ uv)
{
    __shared__ float a[8][DD];
    const int r0 = blockIdx.x * 8, tid = threadIdx.x;
    for (int i = tid; i < 8*DD; i += 256)
        a[i/DD][i%DD] = ct[(size_t)(r0 + i/DD)*DD + i%DD];
    __syncthreads();
    for (int d = tid; d < DD; d += 256) {
        float aq[8]={0,0,0,0,0,0,0,0}, ak[8]={0,0,0,0,0,0,0,0}, av[8]={0,0,0,0,0,0,0,0};
        for (int k = 0; k < DD; ++k) {
            float wq_ = wq[(size_t)k*DD + d];
            float wk_ = wk[(size_t)k*DD + d];
            float wv_ = wv[(size_t)k*DD + d];
            #pragma unroll
            for (int r = 0; r < 8; ++r) {
                float x = a[r][k];
                aq[r] += x*wq_; ak[r] += x*wk_; av[r] += x*wv_;
            }
        }
        for (int r = 0; r < 8; ++r) {
            uq[(size_t)(r0+r)*DD + d] = aq[r];
            uk[(size_t)(r0+r)*DD + d] = ak[r];
            uv[(size_t)(r0+r)*DD + d] = av[r];
        }
    }
}

// ---------------------------------------------------------------------------
// K3c: masked MHSA per (batch, head); block = 64 threads
// ---------------------------------------------------------------------------
__global__ __launch_bounds__(64) void user_attn(
    const float* __restrict__ uq, const float* __restrict__ uk,
    const float* __restrict__ uv, const int* __restrict__ map,
    float* __restrict__ uo)
{
    const int b = blockIdx.x / HH, h = blockIdx.x % HH, tid = threadIdx.x;
    __shared__ float q[NCK][DHD], k[NCK][DHD], v[NCK][DHD];
    __shared__ float sc[NCK][NCK+2];
    __shared__ float biasl[NCK];
    for (int i = tid; i < NCK*DHD; i += 64) {
        int c = i/DHD, d = i%DHD;
        size_t base = ((size_t)b*NCK + c)*DD + h*DHD + d;
        q[c][d] = uq[base]; k[c][d] = uk[base]; v[c][d] = uv[base];
    }
    for (int i = tid; i < NCK; i += 64)
        biasl[i] = (map[b*NCK + i] >= 0) ? 0.f : -1e9f;
    __syncthreads();
    for (int i = tid; i < NCK*NCK; i += 64) {
        int t = i/NCK, k2 = i%NCK;
        float s = 0.f;
        #pragma unroll
        for (int d4 = 0; d4 < 5; ++d4) {
            const float4 qa = *(const float4*)&q[t][d4*4];
            const float4 kb = *(const float4*)&k[k2][d4*4];
            s += qa.x*kb.x + qa.y*kb.y + qa.z*kb.z + qa.w*kb.w;
        }
        sc[t][k2] = s * 0.2236067977f + biasl[k2];
    }
    __syncthreads();
    if (tid < NCK) {
        float mx = -1e30f;
        for (int k2 = 0; k2 < NCK; ++k2) mx = fmaxf(mx, sc[tid][k2]);
        float ssum = 0.f;
        for (int k2 = 0; k2 < NCK; ++k2) { float e = __expf(sc[tid][k2]-mx); sc[tid][k2] = e; ssum += e; }
        float inv = 1.f/ssum;
        for (int k2 = 0; k2 < NCK; ++k2) sc[tid][k2] *= inv;
    }
    __syncthreads();
    for (int i = tid; i < NCK*DHD; i += 64) {
        int t = i/DHD, d = i%DHD;
        float o = 0.f;
        for (int k2 = 0; k2 < NCK; ++k2) o += sc[t][k2]*v[k2][d];
        uo[((size_t)b*NCK + t)*DD + h*DHD + d] = o;
    }
}

// ---------------------------------------------------------------------------
// K3d: masked attention pooling -> user_emb[b][400]; block per batch
// ---------------------------------------------------------------------------
__global__ __launch_bounds__(256) void user_pool(
    const float* __restrict__ uo, const int* __restrict__ map,
    const float* __restrict__ uwp, const float* __restrict__ uqp,
    float* __restrict__ user_emb)
{
    const int b = blockIdx.x, tid = threadIdx.x;
    __shared__ float alpha[64];
    __shared__ float red[256];
    for (int t = 0; t < NCK; ++t) {
        float partial = 0.f;
        const float* ur = uo + ((size_t)b*NCK + t)*DD;
        for (int p = tid; p < PP; p += 256) {
            float s = 0.f;
            for (int d = 0; d < DD; ++d) s += ur[d] * uwp[(size_t)d*PP + p];
            partial += tanhf(s) * uqp[p];
        }
        red[tid] = partial; __syncthreads();
        for (int st = 128; st > 0; st >>= 1) {
            if (tid < st) red[tid] += red[tid+st];
            __syncthreads();
        }
        if (tid == 0)
            alpha[t] = red[0] + ((map[b*NCK + t] >= 0) ? 0.f : -1e9f);
        __syncthreads();
    }
    if (tid == 0) {
        float mx = -1e30f;
        for (int t = 0; t < NCK; ++t) mx = fmaxf(mx, alpha[t]);
        float ssum = 0.f;
        for (int t = 0; t < NCK; ++t) { float e = __expf(alpha[t]-mx); alpha[t] = e; ssum += e; }
        float inv = 1.f/ssum;
        for (int t = 0; t < NCK; ++t) alpha[t] *= inv;
    }
    __syncthreads();
    for (int d = tid; d < DD; d += 256) {
        float acc = 0.f;
        for (int t = 0; t < NCK; ++t) acc += alpha[t] * uo[((size_t)b*NCK + t)*DD + d];
        user_emb[(size_t)b*DD + d] = acc;
    }
}

// ---------------------------------------------------------------------------
// K5: candidate scoring + NCE loss; single block
// ---------------------------------------------------------------------------
__global__ __launch_bounds__(256) void score_loss(
    const float* __restrict__ cr, const float* __restrict__ cf,
    const float* __restrict__ ue, const int* __restrict__ label,
    float* __restrict__ dout)
{
    __shared__ float sr[BB][NCAND], sf[BB][NCAND], red[BB];
    const int tid = threadIdx.x;
    for (int i = tid; i < 2*BB*NCAND; i += 256) {
        int which = i / (BB*NCAND);
        int r = i % (BB*NCAND);
        int b = r / NCAND, c = r % NCAND;
        const float* ce = (which ? cf : cr) + (size_t)r*DD;
        const float* u = ue + (size_t)b*DD;
        float s = 0.f;
        for (int d = 0; d < DD; ++d) s += ce[d]*u[d];
        if (which) sf[b][c] = s; else sr[b][c] = s;
        dout[1 + i] = s;
    }
    __syncthreads();
    if (tid < BB) {
        int b = tid;
        float mr = -1e30f, mf = -1e30f;
        for (int c = 0; c < NCAND; ++c) { mr = fmaxf(mr, sr[b][c]); mf = fmaxf(mf, sf[b][c]); }
        float er = 0.f, ef = 0.f;
        for (int c = 0; c < NCAND; ++c) { er += expf(sr[b][c]-mr); ef += expf(sf[b][c]-mf); }
        float lser = logf(er)+mr, lsef = logf(ef)+mf;
        int lab = label[b]; lab = lab < 0 ? 0 : (lab > NCAND-1 ? NCAND-1 : lab);
        float crb = lser - sr[b][lab];
        float cfb = 0.f;
        for (int c = 0; c < NCAND; ++c) cfb += (lsef - sf[b][c]);
        red[tid] = crb + 0.5f * (cfb / (float)NCAND);
    }
    __syncthreads();
    if (tid == 0) {
        float L = 0.f;
        for (int b = 0; b < BB; ++b) L += red[b];
        dout[0] = L / (float)BB;
    }
}

// ---------------------------------------------------------------------------
extern "C" void kernel_launch(void* const* d_in, const int* in_sizes, int n_in,
                              void* d_out, int out_size, void* d_ws, size_t ws_size,
                              hipStream_t stream) {
    (void)in_sizes; (void)n_in; (void)out_size; (void)ws_size;
    const int*   sub_x  = (const int*)d_in[0];
    const int*   edge   = (const int*)d_in[1];
    const int*   mapi   = (const int*)d_in[2];
    const int*   cand   = (const int*)d_in[3];
    const int*   fcand  = (const int*)d_in[4];
    const int*   label  = (const int*)d_in[5];
    const float* glove  = (const float*)d_in[6];
    const float* nwq    = (const float*)d_in[7];
    const float* nwk    = (const float*)d_in[8];
    const float* nwv    = (const float*)d_in[9];
    const float* nwp    = (const float*)d_in[10];
    const float* nqp    = (const float*)d_in[11];
    const float* ggc    = (const float*)d_in[12];
    const float* wih    = (const float*)d_in[13];
    const float* whh    = (const float*)d_in[14];
    const float* bih    = (const float*)d_in[15];
    const float* bhh    = (const float*)d_in[16];
    const float* wclick = (const float*)d_in[17];
    const float* bclick = (const float*)d_in[18];
    const float* uwq    = (const float*)d_in[19];
    const float* uwk    = (const float*)d_in[20];
    const float* uwv    = (const float*)d_in[21];
    const float* uwp    = (const float*)d_in[22];
    const float* uqp    = (const float*)d_in[23];

    // workspace layout (floats); ws_size = 256 MB
    float* ws     = (float*)d_ws;
    float* x_enc  = ws;                       // 4,000,000 f
    float* hbuf   = ws + 4000000;             // 4,000,000 f
    float* region = ws + 8000000;             // 8,000,000 f shared region
    float* mbuf   = region;                   // GGC: m
    float* aggbuf = region + 4000000;         // GGC: agg
    // after GGC, region reused:
    float* ct   = region;                     // 1,280,000
    float* uq   = region + 1280000;
    float* uk   = region + 2560000;
    float* uv   = region + 3840000;
    float* uo   = region + 5120000;           // 1,280,000
    float* user = region + 6400000;           // 25,600
    float* crnc = region + 6425600;           // 128,000
    float* cfnc = region + 6553600;           // 128,000
    // int area at byte offset 64 MB
    int* ibase   = (int*)((char*)d_ws + (size_t)64*1024*1024);
    int* cnt     = ibase;                     // 10,000
    int* off     = ibase + 10000;             // 10,000
    int* cursor  = ibase + 20000;             // 10,000
    int* srclist = ibase + 30000;             // 200,000

    // 1) encode all nodes
    news_enc<<<NN, 256, 0, stream>>>(sub_x, TOKS, glove, nwq, nwk, nwv, nwp, nqp, x_enc);

    // 1b) build CSR-by-destination once (reused by all 3 GGC layers)
    hipMemsetAsync(cnt, 0, NN*sizeof(int), stream);
    count_edges<<<(EE+255)/256, 256, 0, stream>>>(edge, cnt);
    build_offsets<<<1, 256, 0, stream>>>(cnt, off, cursor);
    fill_csr<<<(EE+255)/256, 256, 0, stream>>>(edge, cursor, srclist);

    // 2) GatedGraphConv x3 (gather instead of atomic scatter)
    const float* hin = x_enc;
    for (int l = 0; l < 3; ++l) {
        mm_nodes<<<NN/8, 256, 0, stream>>>(hin, ggc + (size_t)l*DD*DD, mbuf);
        gather_agg<<<NN, 256, 0, stream>>>(mbuf, off, cnt, srclist, aggbuf);
        gru_step<<<NN/8, 256, 0, stream>>>(aggbuf, hin, wih, whh, bih, bhh, hbuf);
        hin = hbuf;
    }

    // 3) click + user encoder
    clicked_mm<<<(BB*NCK)/8, 256, 0, stream>>>(mapi, x_enc, hbuf, wclick, bclick, ct);
    user_qkv<<<(BB*NCK)/8, 256, 0, stream>>>(ct, uwq, uwk, uwv, uq, uk, uv);
    user_attn<<<BB*HH, 64, 0, stream>>>(uq, uk, uv, mapi, uo);
    user_pool<<<BB, 256, 0, stream>>>(uo, mapi, uwp, uqp, user);

    // 4) candidates
    news_enc<<<BB*NCAND, 256, 0, stream>>>(cand,  TOKS, glove, nwq, nwk, nwv, nwp, nqp, crnc);
    news_enc<<<BB*NCAND, 256, 0, stream>>>(fcand, TOKS, glove, nwq, nwk, nwv, nwp, nqp, cfnc);

    // 5) scores + loss
    score_loss<<<1, 256, 0, stream>>>(crnc, cfnc, user, label, (float*)d_out);
}

// Round 4
// 13370.157 us; speedup vs baseline: 27.4734x; 27.4734x over previous
//
#include <hip/hip_runtime.h>
#include <cmath>

#define NN 10000
#define EE 200000
#define BB 64
#define NCK 50
#define NCAND 5
#define TOKS 38
#define TITLE 30
#define GDIM 300
#define HH 20
#define DHD 20
#define DD 400
#define PP 200

__device__ __forceinline__ float bf2f(unsigned short u) {
    return __uint_as_float(((unsigned int)u) << 16);
}
__device__ __forceinline__ unsigned short f2bf(float f) {
    unsigned int u = __float_as_uint(f);
    u += 0x7fffu + ((u >> 16) & 1u);
    return (unsigned short)(u >> 16);
}

// ---------------------------------------------------------------------------
// K1: fused news encoder, register-light restructure.
// One block (256 thr) per item. LDS ~75KB -> 2 blocks/CU.
// Head-groups of 4: QKV cols (240 threads, acc[30] static-unrolled),
// then attention for those 4 heads, accumulate out[30][400] bf16.
// ---------------------------------------------------------------------------
__global__ __launch_bounds__(256) void news_enc(
    const int* __restrict__ tokens, int tok_stride,
    const float* __restrict__ glove,
    const float* __restrict__ wq, const float* __restrict__ wk,
    const float* __restrict__ wv,
    const float* __restrict__ wp, const float* __restrict__ qp,
    float* __restrict__ out_enc)
{
    __shared__ unsigned short embS[TITLE][GDIM];   // 18000 B bf16 [t][k]
    __shared__ unsigned short qkvS[3][TITLE][96];  // 17280 B bf16, head-dim padded 20->24
    __shared__ float scS[4][TITLE][32];            // 15360 B f32 scores
    __shared__ unsigned short outS[TITLE][DD];     // 24000 B bf16 attention out
    __shared__ int   tokS[32];
    __shared__ float alphaS[32];
    __shared__ float redS[8];

    const int tid  = threadIdx.x;
    const int item = blockIdx.x;

    if (tid < TITLE) tokS[tid] = tokens[(size_t)item * tok_stride + tid];
    __syncthreads();

    // ---- Phase A: gather glove rows -> embS (bf16) ----
    for (int i = tid; i < TITLE * 75; i += 256) {
        int t = i / 75, g4 = i % 75;
        const float4 v = *(const float4*)&glove[(size_t)tokS[t] * GDIM + g4 * 4];
        embS[t][g4*4+0] = f2bf(v.x);
        embS[t][g4*4+1] = f2bf(v.y);
        embS[t][g4*4+2] = f2bf(v.z);
        embS[t][g4*4+3] = f2bf(v.w);
    }
    __syncthreads();

    const int d    = tid;        // QKV column within head-group (0..239 active)
    const int m    = d / 80;     // 0=q 1=k 2=v
    const int c    = d % 80;
    const int hloc = c / 20, dloc = c % 20;
    const float* Wm = (m == 0) ? wq : ((m == 1) ? wk : wv);

    for (int hg = 0; hg < 5; ++hg) {
        // ---- B1: QKV columns for heads hg*4 .. hg*4+3 ----
        if (tid < 240) {
            const float* wcol = Wm + (hg*80 + c);
            float acc[TITLE];
            #pragma unroll
            for (int r = 0; r < TITLE; ++r) acc[r] = 0.f;
            for (int k4 = 0; k4 < 75; ++k4) {
                float w0 = wcol[(size_t)(k4*4+0)*DD];
                float w1 = wcol[(size_t)(k4*4+1)*DD];
                float w2 = wcol[(size_t)(k4*4+2)*DD];
                float w3 = wcol[(size_t)(k4*4+3)*DD];
                #pragma unroll
                for (int r = 0; r < TITLE; ++r) {
                    const uint2 pk = *(const uint2*)&embS[r][k4*4];
                    float e0 = __uint_as_float(pk.x << 16);
                    float e1 = __uint_as_float(pk.x & 0xffff0000u);
                    float e2 = __uint_as_float(pk.y << 16);
                    float e3 = __uint_as_float(pk.y & 0xffff0000u);
                    acc[r] += e0*w0 + e1*w1 + e2*w2 + e3*w3;
                }
            }
            #pragma unroll
            for (int r = 0; r < TITLE; ++r)
                qkvS[m][r][hloc*24 + dloc] = f2bf(acc[r]);
        }
        __syncthreads();

        // ---- B2a: scores = q k^T / sqrt(20) for 4 heads ----
        for (int i = tid; i < 4*TITLE*TITLE; i += 256) {
            int h2 = i / (TITLE*TITLE), rem = i % (TITLE*TITLE);
            int t = rem / TITLE, k2 = rem % TITLE;
            float s = 0.f;
            #pragma unroll
            for (int d0 = 0; d0 < 5; ++d0) {
                const uint2 qa = *(const uint2*)&qkvS[0][t][h2*24 + d0*4];
                const uint2 kb = *(const uint2*)&qkvS[1][k2][h2*24 + d0*4];
                float q0 = __uint_as_float(qa.x << 16);
                float q1 = __uint_as_float(qa.x & 0xffff0000u);
                float q2 = __uint_as_float(qa.y << 16);
                float q3 = __uint_as_float(qa.y & 0xffff0000u);
                float b0 = __uint_as_float(kb.x << 16);
                float b1 = __uint_as_float(kb.x & 0xffff0000u);
                float b2 = __uint_as_float(kb.y << 16);
                float b3 = __uint_as_float(kb.y & 0xffff0000u);
                s += q0*b0 + q1*b1 + q2*b2 + q3*b3;
            }
            scS[h2][t][k2] = s * 0.2236067977f;
        }
        __syncthreads();

        // ---- B2b: row softmax ----
        if (tid < 4*TITLE) {
            int h2 = tid / TITLE, t = tid % TITLE;
            float mx = -1e30f;
            for (int k2 = 0; k2 < TITLE; ++k2) mx = fmaxf(mx, scS[h2][t][k2]);
            float ss = 0.f;
            for (int k2 = 0; k2 < TITLE; ++k2) {
                float e = __expf(scS[h2][t][k2] - mx);
                scS[h2][t][k2] = e; ss += e;
            }
            float inv = 1.f / ss;
            for (int k2 = 0; k2 < TITLE; ++k2) scS[h2][t][k2] *= inv;
        }
        __syncthreads();

        // ---- B2c: out = att @ v ----
        for (int i = tid; i < 4*TITLE*DHD; i += 256) {
            int h2 = i / (TITLE*DHD), rem = i % (TITLE*DHD);
            int t = rem / DHD, dd = rem % DHD;
            float o = 0.f;
            for (int k2 = 0; k2 < TITLE; ++k2)
                o += scS[h2][t][k2] * bf2f(qkvS[2][k2][h2*24 + dd]);
            outS[t][hg*80 + h2*20 + dd] = f2bf(o);
        }
        __syncthreads();
    }

    // ---- Phase C: token attention pooling ----
    const float qpv = (tid < PP) ? qp[tid] : 0.f;
    for (int t0 = 0; t0 < TITLE; t0 += 3) {
        float s0 = 0.f, s1 = 0.f, s2 = 0.f;
        if (tid < PP) {
            for (int d4 = 0; d4 < 100; ++d4) {
                float w0 = wp[(size_t)(d4*4+0)*PP + tid];
                float w1 = wp[(size_t)(d4*4+1)*PP + tid];
                float w2 = wp[(size_t)(d4*4+2)*PP + tid];
                float w3 = wp[(size_t)(d4*4+3)*PP + tid];
                const uint2 p0 = *(const uint2*)&outS[t0+0][d4*4];
                const uint2 p1 = *(const uint2*)&outS[t0+1][d4*4];
                const uint2 p2 = *(const uint2*)&outS[t0+2][d4*4];
                s0 += __uint_as_float(p0.x << 16)*w0 + __uint_as_float(p0.x & 0xffff0000u)*w1
                    + __uint_as_float(p0.y << 16)*w2 + __uint_as_float(p0.y & 0xffff0000u)*w3;
                s1 += __uint_as_float(p1.x << 16)*w0 + __uint_as_float(p1.x & 0xffff0000u)*w1
                    + __uint_as_float(p1.y << 16)*w2 + __uint_as_float(p1.y & 0xffff0000u)*w3;
                s2 += __uint_as_float(p2.x << 16)*w0 + __uint_as_float(p2.x & 0xffff0000u)*w1
                    + __uint_as_float(p2.y << 16)*w2 + __uint_as_float(p2.y & 0xffff0000u)*w3;
            }
        }
        #pragma unroll
        for (int j = 0; j < 3; ++j) {
            float v = tanhf(j == 0 ? s0 : (j == 1 ? s1 : s2)) * qpv;
            for (int off = 32; off; off >>= 1) v += __shfl_down(v, off);
            if ((tid & 63) == 0) redS[tid >> 6] = v;
            __syncthreads();
            if (tid == 0) alphaS[t0 + j] = redS[0] + redS[1] + redS[2] + redS[3];
            __syncthreads();
        }
    }
    if (tid == 0) {
        float mx = -1e30f;
        for (int t = 0; t < TITLE; ++t) mx = fmaxf(mx, alphaS[t]);
        float ss = 0.f;
        for (int t = 0; t < TITLE; ++t) { float e = __expf(alphaS[t]-mx); alphaS[t] = e; ss += e; }
        float inv = 1.f / ss;
        for (int t = 0; t < TITLE; ++t) alphaS[t] *= inv;
    }
    __syncthreads();
    for (int dd = tid; dd < DD; dd += 256) {
        float a = 0.f;
        for (int t = 0; t < TITLE; ++t) a += alphaS[t] * bf2f(outS[t][dd]);
        out_enc[(size_t)item*DD + dd] = a;
    }
}

// ---------------------------------------------------------------------------
// K2a: m = h @ W  ([N,400]@[400,400]); 8 rows per block
// ---------------------------------------------------------------------------
__global__ __launch_bounds__(256) void mm_nodes(
    const float* __restrict__ A, const float* __restrict__ W, float* __restrict__ Mo)
{
    __shared__ float a[8][DD];
    const int r0 = blockIdx.x * 8, tid = threadIdx.x;
    for (int i = tid; i < 8*DD; i += 256)
        a[i/DD][i%DD] = A[(size_t)(r0 + i/DD)*DD + i%DD];
    __syncthreads();
    for (int d = tid; d < DD; d += 256) {
        float acc[8] = {0,0,0,0,0,0,0,0};
        for (int k4 = 0; k4 < 100; ++k4) {
            float w0 = W[(size_t)(k4*4+0)*DD + d];
            float w1 = W[(size_t)(k4*4+1)*DD + d];
            float w2 = W[(size_t)(k4*4+2)*DD + d];
            float w3 = W[(size_t)(k4*4+3)*DD + d];
            #pragma unroll
            for (int r = 0; r < 8; ++r) {
                const float4 av = *(const float4*)&a[r][k4*4];
                acc[r] += av.x*w0 + av.y*w1 + av.z*w2 + av.w*w3;
            }
        }
        #pragma unroll
        for (int r = 0; r < 8; ++r) Mo[(size_t)(r0+r)*DD + d] = acc[r];
    }
}

// ---------------------------------------------------------------------------
// CSR build: count -> exclusive scan -> cursor scatter
// ---------------------------------------------------------------------------
__global__ __launch_bounds__(256) void count_edges(
    const int* __restrict__ ei, int* __restrict__ cnt)
{
    int e = blockIdx.x * 256 + threadIdx.x;
    if (e < EE) atomicAdd(&cnt[ei[EE + e]], 1);
}

__global__ __launch_bounds__(256) void build_offsets(
    const int* __restrict__ cnt, int* __restrict__ off, int* __restrict__ cursor)
{
    __shared__ int csum[256];
    const int tid = threadIdx.x;
    const int chunk = (NN + 255) / 256;   // 40
    int s = 0;
    for (int i = 0; i < chunk; ++i) {
        int idx = tid * chunk + i;
        if (idx < NN) s += cnt[idx];
    }
    csum[tid] = s;
    __syncthreads();
    if (tid == 0) {
        int run = 0;
        for (int i = 0; i < 256; ++i) { int c = csum[i]; csum[i] = run; run += c; }
    }
    __syncthreads();
    int run = csum[tid];
    for (int i = 0; i < chunk; ++i) {
        int idx = tid * chunk + i;
        if (idx < NN) {
            off[idx] = run; cursor[idx] = run;
            run += cnt[idx];
        }
    }
}

__global__ __launch_bounds__(256) void fill_csr(
    const int* __restrict__ ei, int* __restrict__ cursor, int* __restrict__ srclist)
{
    int e = blockIdx.x * 256 + threadIdx.x;
    if (e < EE) {
        int d = ei[EE + e];
        int pos = atomicAdd(&cursor[d], 1);
        srclist[pos] = ei[e];
    }
}

// ---------------------------------------------------------------------------
// K2b: agg[node] = sum over incoming edges of m[src]  (no float atomics)
// ---------------------------------------------------------------------------
__global__ __launch_bounds__(256) void gather_agg(
    const float* __restrict__ m, const int* __restrict__ off,
    const int* __restrict__ cnt, const int* __restrict__ srclist,
    float* __restrict__ agg)
{
    __shared__ int sl[128];
    const int node = blockIdx.x, tid = threadIdx.x;
    const int o0 = off[node], deg = cnt[node];
    float acc0 = 0.f, acc1 = 0.f;
    const int d0 = tid, d1 = tid + 256;          // d1 valid if < 400
    for (int j0 = 0; j0 < deg; j0 += 128) {
        if (tid < 128 && j0 + tid < deg) sl[tid] = srclist[o0 + j0 + tid];
        __syncthreads();
        const int jn = (deg - j0 < 128) ? (deg - j0) : 128;
        for (int j = 0; j < jn; ++j) {
            const float* mr = &m[(size_t)sl[j] * DD];
            acc0 += mr[d0];
            if (d1 < DD) acc1 += mr[d1];
        }
        __syncthreads();
    }
    agg[(size_t)node * DD + d0] = acc0;
    if (d1 < DD) agg[(size_t)node * DD + d1] = acc1;
}

// ---------------------------------------------------------------------------
// K2c: fused GRU cell; 8 rows per block.
// ---------------------------------------------------------------------------
__global__ __launch_bounds__(256) void gru_step(
    const float* __restrict__ agg, const float* __restrict__ hin,
    const float* __restrict__ wih, const float* __restrict__ whh,
    const float* __restrict__ bih, const float* __restrict__ bhh,
    float* __restrict__ hout)
{
    __shared__ float al[8][DD], hl[8][DD];
    const int r0 = blockIdx.x * 8, tid = threadIdx.x;
    for (int i = tid; i < 8*DD; i += 256) {
        int r = i/DD, k = i%DD;
        al[r][k] = agg[(size_t)(r0+r)*DD + k];
        hl[r][k] = hin[(size_t)(r0+r)*DD + k];
    }
    __syncthreads();
    for (int d = tid; d < DD; d += 256) {
        float air[8]={0,0,0,0,0,0,0,0}, aiz[8]={0,0,0,0,0,0,0,0}, ain[8]={0,0,0,0,0,0,0,0};
        float ahr[8]={0,0,0,0,0,0,0,0}, ahz[8]={0,0,0,0,0,0,0,0}, ahn[8]={0,0,0,0,0,0,0,0};
        for (int k = 0; k < DD; ++k) {
            const float* wi = &wih[(size_t)k*1200 + d];
            float wir = wi[0], wiz = wi[400], win = wi[800];
            const float* wh = &whh[(size_t)k*1200 + d];
            float whr = wh[0], whz = wh[400], whn = wh[800];
            #pragma unroll
            for (int r = 0; r < 8; ++r) {
                float a = al[r][k], hh = hl[r][k];
                air[r] += a*wir; aiz[r] += a*wiz; ain[r] += a*win;
                ahr[r] += hh*whr; ahz[r] += hh*whz; ahn[r] += hh*whn;
            }
        }
        float bir = bih[d], biz = bih[d+400], bin = bih[d+800];
        float bhr = bhh[d], bhz = bhh[d+400], bhn = bhh[d+800];
        #pragma unroll
        for (int r = 0; r < 8; ++r) {
            float rg = 1.f/(1.f + __expf(-(air[r]+bir + ahr[r]+bhr)));
            float zg = 1.f/(1.f + __expf(-(aiz[r]+biz + ahz[r]+bhz)));
            float ng = tanhf(ain[r]+bin + rg*(ahn[r]+bhn));
            hout[(size_t)(r0+r)*DD + d] = (1.f-zg)*ng + zg*hl[r][d];
        }
    }
}

// ---------------------------------------------------------------------------
// K3a: clicked_total = concat(x_enc[midx], h[midx])*mask @ w_click + b_click
// ---------------------------------------------------------------------------
__global__ __launch_bounds__(256) void clicked_mm(
    const int* __restrict__ map, const float* __restrict__ xe,
    const float* __restrict__ hg, const float* __restrict__ wc,
    const float* __restrict__ bc, float* __restrict__ ct)
{
    __shared__ float a[8][2*DD];
    const int r0 = blockIdx.x * 8, tid = threadIdx.x;
    for (int i = tid; i < 8*2*DD; i += 256) {
        int r = i/(2*DD), k = i%(2*DD);
        int mi = map[r0 + r];
        float v = 0.f;
        if (mi >= 0) v = (k < DD) ? xe[(size_t)mi*DD + k] : hg[(size_t)mi*DD + (k-DD)];
        a[r][k] = v;
    }
    __syncthreads();
    for (int d = tid; d < DD; d += 256) {
        float acc[8] = {0,0,0,0,0,0,0,0};
        for (int k = 0; k < 2*DD; ++k) {
            float w = wc[(size_t)k*DD + d];
            #pragma unroll
            for (int r = 0; r < 8; ++r) acc[r] += a[r][k]*w;
        }
        float bb = bc[d];
        #pragma unroll
        for (int r = 0; r < 8; ++r) ct[(size_t)(r0+r)*DD + d] = acc[r] + bb;
    }
}

// ---------------------------------------------------------------------------
// K3b: uq/uk/uv = ct @ u_wq/u_wk/u_wv
// ---------------------------------------------------------------------------
__global__ __launch_bounds__(256) void user_qkv(
    const float* __restrict__ ct,
    const float* __restrict__ wq, const float* __restrict__ wk, const float* __restrict__ wv,
    float* __restrict__ uq, float* __restrict__ uk, float* __restrict__ uv)
{
    __shared__ float a[8][DD];
    const int r0 = blockIdx.x * 8, tid = threadIdx.x;
    for (int i = tid; i < 8*DD; i += 256)
        a[i/DD][i%DD] = ct[(size_t)(r0 + i/DD)*DD + i%DD];
    __syncthreads();
    for (int d = tid; d < DD; d += 256) {
        float aq[8]={0,0,0,0,0,0,0,0}, ak[8]={0,0,0,0,0,0,0,0}, av[8]={0,0,0,0,0,0,0,0};
        for (int k = 0; k < DD; ++k) {
            float wq_ = wq[(size_t)k*DD + d];
            float wk_ = wk[(size_t)k*DD + d];
            float wv_ = wv[(size_t)k*DD + d];
            #pragma unroll
            for (int r = 0; r < 8; ++r) {
                float x = a[r][k];
                aq[r] += x*wq_; ak[r] += x*wk_; av[r] += x*wv_;
            }
        }
        #pragma unroll
        for (int r = 0; r < 8; ++r) {
            uq[(size_t)(r0+r)*DD + d] = aq[r];
            uk[(size_t)(r0+r)*DD + d] = ak[r];
            uv[(size_t)(r0+r)*DD + d] = av[r];
        }
    }
}

// ---------------------------------------------------------------------------
// K3c: masked MHSA per (batch, head); block = 64 threads
// ---------------------------------------------------------------------------
__global__ __launch_bounds__(64) void user_attn(
    const float* __restrict__ uq, const float* __restrict__ uk,
    const float* __restrict__ uv, const int* __restrict__ map,
    float* __restrict__ uo)
{
    const int b = blockIdx.x / HH, h = blockIdx.x % HH, tid = threadIdx.x;
    __shared__ float q[NCK][DHD], k[NCK][DHD], v[NCK][DHD];
    __shared__ float sc[NCK][NCK+2];
    __shared__ float biasl[NCK];
    for (int i = tid; i < NCK*DHD; i += 64) {
        int c = i/DHD, d = i%DHD;
        size_t base = ((size_t)b*NCK + c)*DD + h*DHD + d;
        q[c][d] = uq[base]; k[c][d] = uk[base]; v[c][d] = uv[base];
    }
    for (int i = tid; i < NCK; i += 64)
        biasl[i] = (map[b*NCK + i] >= 0) ? 0.f : -1e9f;
    __syncthreads();
    for (int i = tid; i < NCK*NCK; i += 64) {
        int t = i/NCK, k2 = i%NCK;
        float s = 0.f;
        #pragma unroll
        for (int d4 = 0; d4 < 5; ++d4) {
            const float4 qa = *(const float4*)&q[t][d4*4];
            const float4 kb = *(const float4*)&k[k2][d4*4];
            s += qa.x*kb.x + qa.y*kb.y + qa.z*kb.z + qa.w*kb.w;
        }
        sc[t][k2] = s * 0.2236067977f + biasl[k2];
    }
    __syncthreads();
    if (tid < NCK) {
        float mx = -1e30f;
        for (int k2 = 0; k2 < NCK; ++k2) mx = fmaxf(mx, sc[tid][k2]);
        float ssum = 0.f;
        for (int k2 = 0; k2 < NCK; ++k2) { float e = __expf(sc[tid][k2]-mx); sc[tid][k2] = e; ssum += e; }
        float inv = 1.f/ssum;
        for (int k2 = 0; k2 < NCK; ++k2) sc[tid][k2] *= inv;
    }
    __syncthreads();
    for (int i = tid; i < NCK*DHD; i += 64) {
        int t = i/DHD, d = i%DHD;
        float o = 0.f;
        for (int k2 = 0; k2 < NCK; ++k2) o += sc[t][k2]*v[k2][d];
        uo[((size_t)b*NCK + t)*DD + h*DHD + d] = o;
    }
}

// ---------------------------------------------------------------------------
// K3d: masked attention pooling -> user_emb[b][400]; block per batch
// ---------------------------------------------------------------------------
__global__ __launch_bounds__(256) void user_pool(
    const float* __restrict__ uo, const int* __restrict__ map,
    const float* __restrict__ uwp, const float* __restrict__ uqp,
    float* __restrict__ user_emb)
{
    const int b = blockIdx.x, tid = threadIdx.x;
    __shared__ float alpha[64];
    __shared__ float red[256];
    for (int t = 0; t < NCK; ++t) {
        float partial = 0.f;
        const float* ur = uo + ((size_t)b*NCK + t)*DD;
        for (int p = tid; p < PP; p += 256) {
            float s = 0.f;
            for (int d = 0; d < DD; ++d) s += ur[d] * uwp[(size_t)d*PP + p];
            partial += tanhf(s) * uqp[p];
        }
        red[tid] = partial; __syncthreads();
        for (int st = 128; st > 0; st >>= 1) {
            if (tid < st) red[tid] += red[tid+st];
            __syncthreads();
        }
        if (tid == 0)
            alpha[t] = red[0] + ((map[b*NCK + t] >= 0) ? 0.f : -1e9f);
        __syncthreads();
    }
    if (tid == 0) {
        float mx = -1e30f;
        for (int t = 0; t < NCK; ++t) mx = fmaxf(mx, alpha[t]);
        float ssum = 0.f;
        for (int t = 0; t < NCK; ++t) { float e = __expf(alpha[t]-mx); alpha[t] = e; ssum += e; }
        float inv = 1.f/ssum;
        for (int t = 0; t < NCK; ++t) alpha[t] *= inv;
    }
    __syncthreads();
    for (int d = tid; d < DD; d += 256) {
        float acc = 0.f;
        for (int t = 0; t < NCK; ++t) acc += alpha[t] * uo[((size_t)b*NCK + t)*DD + d];
        user_emb[(size_t)b*DD + d] = acc;
    }
}

// ---------------------------------------------------------------------------
// K5: candidate scoring + NCE loss; single block
// ---------------------------------------------------------------------------
__global__ __launch_bounds__(256) void score_loss(
    const float* __restrict__ cr, const float* __restrict__ cf,
    const float* __restrict__ ue, const int* __restrict__ label,
    float* __restrict__ dout)
{
    __shared__ float sr[BB][NCAND], sf[BB][NCAND], red[BB];
    const int tid = threadIdx.x;
    for (int i = tid; i < 2*BB*NCAND; i += 256) {
        int which = i / (BB*NCAND);
        int r = i % (BB*NCAND);
        int b = r / NCAND, c = r % NCAND;
        const float* ce = (which ? cf : cr) + (size_t)r*DD;
        const float* u = ue + (size_t)b*DD;
        float s = 0.f;
        for (int d = 0; d < DD; ++d) s += ce[d]*u[d];
        if (which) sf[b][c] = s; else sr[b][c] = s;
        dout[1 + i] = s;
    }
    __syncthreads();
    if (tid < BB) {
        int b = tid;
        float mr = -1e30f, mf = -1e30f;
        for (int c = 0; c < NCAND; ++c) { mr = fmaxf(mr, sr[b][c]); mf = fmaxf(mf, sf[b][c]); }
        float er = 0.f, ef = 0.f;
        for (int c = 0; c < NCAND; ++c) { er += expf(sr[b][c]-mr); ef += expf(sf[b][c]-mf); }
        float lser = logf(er)+mr, lsef = logf(ef)+mf;
        int lab = label[b]; lab = lab < 0 ? 0 : (lab > NCAND-1 ? NCAND-1 : lab);
        float crb = lser - sr[b][lab];
        float cfb = 0.f;
        for (int c = 0; c < NCAND; ++c) cfb += (lsef - sf[b][c]);
        red[tid] = crb + 0.5f * (cfb / (float)NCAND);
    }
    __syncthreads();
    if (tid == 0) {
        float L = 0.f;
        for (int b = 0; b < BB; ++b) L += red[b];
        dout[0] = L / (float)BB;
    }
}

// ---------------------------------------------------------------------------
extern "C" void kernel_launch(void* const* d_in, const int* in_sizes, int n_in,
                              void* d_out, int out_size, void* d_ws, size_t ws_size,
                              hipStream_t stream) {
    (void)in_sizes; (void)n_in; (void)out_size; (void)ws_size;
    const int*   sub_x  = (const int*)d_in[0];
    const int*   edge   = (const int*)d_in[1];
    const int*   mapi   = (const int*)d_in[2];
    const int*   cand   = (const int*)d_in[3];
    const int*   fcand  = (const int*)d_in[4];
    const int*   label  = (const int*)d_in[5];
    const float* glove  = (const float*)d_in[6];
    const float* nwq    = (const float*)d_in[7];
    const float* nwk    = (const float*)d_in[8];
    const float* nwv    = (const float*)d_in[9];
    const float* nwp    = (const float*)d_in[10];
    const float* nqp    = (const float*)d_in[11];
    const float* ggc    = (const float*)d_in[12];
    const float* wih    = (const float*)d_in[13];
    const float* whh    = (const float*)d_in[14];
    const float* bih    = (const float*)d_in[15];
    const float* bhh    = (const float*)d_in[16];
    const float* wclick = (const float*)d_in[17];
    const float* bclick = (const float*)d_in[18];
    const float* uwq    = (const float*)d_in[19];
    const float* uwk    = (const float*)d_in[20];
    const float* uwv    = (const float*)d_in[21];
    const float* uwp    = (const float*)d_in[22];
    const float* uqp    = (const float*)d_in[23];

    // workspace layout (floats); ws_size = 256 MB
    float* ws     = (float*)d_ws;
    float* x_enc  = ws;                       // 4,000,000 f
    float* hbuf   = ws + 4000000;             // 4,000,000 f
    float* region = ws + 8000000;             // 8,000,000 f shared region
    float* mbuf   = region;                   // GGC: m
    float* aggbuf = region + 4000000;         // GGC: agg
    // after GGC, region reused:
    float* ct   = region;                     // 1,280,000
    float* uq   = region + 1280000;
    float* uk   = region + 2560000;
    float* uv   = region + 3840000;
    float* uo   = region + 5120000;           // 1,280,000
    float* user = region + 6400000;           // 25,600
    float* crnc = region + 6425600;           // 128,000
    float* cfnc = region + 6553600;           // 128,000
    // int area at byte offset 64 MB
    int* ibase   = (int*)((char*)d_ws + (size_t)64*1024*1024);
    int* cnt     = ibase;                     // 10,000
    int* off     = ibase + 10000;             // 10,000
    int* cursor  = ibase + 20000;             // 10,000
    int* srclist = ibase + 30000;             // 200,000

    // 1) encode all nodes
    news_enc<<<NN, 256, 0, stream>>>(sub_x, TOKS, glove, nwq, nwk, nwv, nwp, nqp, x_enc);

    // 1b) build CSR-by-destination once (reused by all 3 GGC layers)
    hipMemsetAsync(cnt, 0, NN*sizeof(int), stream);
    count_edges<<<(EE+255)/256, 256, 0, stream>>>(edge, cnt);
    build_offsets<<<1, 256, 0, stream>>>(cnt, off, cursor);
    fill_csr<<<(EE+255)/256, 256, 0, stream>>>(edge, cursor, srclist);

    // 2) GatedGraphConv x3 (gather instead of atomic scatter)
    const float* hin = x_enc;
    for (int l = 0; l < 3; ++l) {
        mm_nodes<<<NN/8, 256, 0, stream>>>(hin, ggc + (size_t)l*DD*DD, mbuf);
        gather_agg<<<NN, 256, 0, stream>>>(mbuf, off, cnt, srclist, aggbuf);
        gru_step<<<NN/8, 256, 0, stream>>>(aggbuf, hin, wih, whh, bih, bhh, hbuf);
        hin = hbuf;
    }

    // 3) click + user encoder
    clicked_mm<<<(BB*NCK)/8, 256, 0, stream>>>(mapi, x_enc, hbuf, wclick, bclick, ct);
    user_qkv<<<(BB*NCK)/8, 256, 0, stream>>>(ct, uwq, uwk, uwv, uq, uk, uv);
    user_attn<<<BB*HH, 64, 0, stream>>>(uq, uk, uv, mapi, uo);
    user_pool<<<BB, 256, 0, stream>>>(uo, mapi, uwp, uqp, user);

    // 4) candidates
    news_enc<<<BB*NCAND, 256, 0, stream>>>(cand,  TOKS, glove, nwq, nwk, nwv, nwp, nqp, crnc);
    news_enc<<<BB*NCAND, 256, 0, stream>>>(fcand, TOKS, glove, nwq, nwk, nwv, nwp, nqp, cfnc);

    // 5) scores + loss
    score_loss<<<1, 256, 0, stream>>>(crnc, cfnc, user, label, (float*)d_out);
}

// Round 5
// 5094.476 us; speedup vs baseline: 72.1024x; 2.6244x over previous
//
#include <hip/hip_runtime.h>
#include <cmath>

#define NN 10000
#define EE 200000
#define BB 64
#define NCK 50
#define NCAND 5
#define TOKS 38
#define TITLE 30
#define GDIM 300
#define HH 20
#define DHD 20
#define DD 400
#define PP 200

typedef __attribute__((ext_vector_type(8))) short bh8;
typedef __attribute__((ext_vector_type(4))) float f32x4;

__device__ __forceinline__ float bf2f(unsigned short u) {
    return __uint_as_float(((unsigned int)u) << 16);
}
__device__ __forceinline__ unsigned short f2bf(float f) {
    unsigned int u = __float_as_uint(f);
    u += 0x7fffu + ((u >> 16) & 1u);
    return (unsigned short)(u >> 16);
}

// ---------------------------------------------------------------------------
// prep: Wt[1200][320] bf16 = concat(wq,wk,wv) transposed, k-padded with zeros
// ---------------------------------------------------------------------------
__global__ __launch_bounds__(256) void prep_wt(
    const float* __restrict__ wq, const float* __restrict__ wk,
    const float* __restrict__ wv, unsigned short* __restrict__ Wt)
{
    int i = blockIdx.x * 256 + threadIdx.x;
    if (i >= 1200 * 320) return;
    int n = i / 320, k = i % 320;
    int m = n / 400, nn = n % 400;
    const float* W = (m == 0) ? wq : ((m == 1) ? wk : wv);
    float v = (k < GDIM) ? W[(size_t)k * DD + nn] : 0.f;
    Wt[i] = f2bf(v);
}

// prep: wpT[208][416] bf16 = wp[400][200] transposed, padded with zeros
__global__ __launch_bounds__(256) void prep_wpt(
    const float* __restrict__ wp, unsigned short* __restrict__ wpT)
{
    int i = blockIdx.x * 256 + threadIdx.x;
    if (i >= 208 * 416) return;
    int n = i / 416, k = i % 416;
    float v = (n < PP && k < DD) ? wp[(size_t)k * PP + n] : 0.f;
    wpT[i] = f2bf(v);
}

// ---------------------------------------------------------------------------
// K1: fused news encoder with MFMA QKV + MFMA pooling.
// One block (256 thr = 4 waves) per item. LDS ~68KB -> 2 blocks/CU.
// A/B k-slot mapping: both use k=(lane>>4)*8+j -> consistent bijection,
// correct regardless of HW internal k ordering. C/D: col=lane&15,
// row=(lane>>4)*4+reg (HW-verified, learn_hip m89).
// ---------------------------------------------------------------------------
__global__ __launch_bounds__(256) void news_enc(
    const int* __restrict__ tokens, int tok_stride,
    const float* __restrict__ glove,
    const unsigned short* __restrict__ Wt,     // [1200][320] bf16
    const unsigned short* __restrict__ wpT,    // [208][416] bf16
    const float* __restrict__ qp,
    float* __restrict__ out_enc)
{
    // union region: embS [32][328] bf16 (20992B) | scS [4][30][33] f32 (15840B)
    //               | poolP [32][16] f32 (2048B)
    __shared__ __align__(16) unsigned char uS[21056];
    __shared__ __align__(16) unsigned short qkvS[3 * 32 * 100];  // 19200B
    __shared__ __align__(16) unsigned short outS[32 * 424];      // 27136B
    __shared__ int   tokS[32];
    __shared__ float alphaS[32];

    unsigned short* embS = (unsigned short*)uS;            // [32][328]
    float* scF  = (float*)uS;                              // [4][30][33]
    float* poolP = (float*)uS;                             // [32][16]

    const int tid  = threadIdx.x;
    const int item = blockIdx.x;
    const int w    = tid >> 6;        // wave 0..3
    const int lane = tid & 63;
    const int g    = lane >> 4;       // k-group 0..3
    const int l15  = lane & 15;       // row (A) / col (B,C)

    if (tid < TITLE) tokS[tid] = tokens[(size_t)item * tok_stride + tid];
    // zero embS (rows 30/31, k>=300 padding) and outS (rows 30/31, k>=400)
    for (int i = tid; i < (32*328)/2; i += 256) ((unsigned int*)embS)[i] = 0u;
    for (int i = tid; i < (32*424)/2; i += 256) ((unsigned int*)outS)[i] = 0u;
    __syncthreads();

    // gather glove rows -> embS bf16
    for (int i = tid; i < TITLE * 75; i += 256) {
        int t = i / 75, g4 = i % 75;
        const float4 v = *(const float4*)&glove[(size_t)tokS[t] * GDIM + g4 * 4];
        embS[t*328 + g4*4+0] = f2bf(v.x);
        embS[t*328 + g4*4+1] = f2bf(v.y);
        embS[t*328 + g4*4+2] = f2bf(v.z);
        embS[t*328 + g4*4+3] = f2bf(v.w);
    }
    __syncthreads();

    // preload A-fragments: 2 m-tiles x 10 k-steps (80 VGPR)
    bh8 afr[2][10];
    #pragma unroll
    for (int mt = 0; mt < 2; ++mt)
        #pragma unroll
        for (int ks = 0; ks < 10; ++ks)
            afr[mt][ks] = *(const bh8*)&embS[(mt*16 + l15)*328 + ks*32 + g*8];

    for (int hg = 0; hg < 5; ++hg) {
        // ---- QKV via MFMA: 15 n-tiles (q|k|v x 5) over 4 waves ----
        for (int tt = 0; tt < 4; ++tt) {
            int t = w * 4 + tt;
            if (t < 15) {
                int m = t / 5, loc = t % 5;
                const unsigned short* wb =
                    Wt + (size_t)(m*400 + hg*80 + loc*16 + l15) * 320;
                f32x4 c0 = {0.f,0.f,0.f,0.f}, c1 = {0.f,0.f,0.f,0.f};
                #pragma unroll
                for (int ks = 0; ks < 10; ++ks) {
                    bh8 b = *(const bh8*)&wb[ks*32 + g*8];
                    c0 = __builtin_amdgcn_mfma_f32_16x16x32_bf16(afr[0][ks], b, c0, 0, 0, 0);
                    c1 = __builtin_amdgcn_mfma_f32_16x16x32_bf16(afr[1][ks], b, c1, 0, 0, 0);
                }
                int c2 = loc*16 + l15, h2 = c2 / 20, dloc = c2 % 20;
                #pragma unroll
                for (int r = 0; r < 4; ++r) {
                    qkvS[(m*32 + g*4+r)*100 + h2*24 + dloc]    = f2bf(c0[r]);
                    qkvS[(m*32 + 16+g*4+r)*100 + h2*24 + dloc] = f2bf(c1[r]);
                }
            }
        }
        __syncthreads();

        // ---- scores = q k^T / sqrt(20) for 4 heads ----
        for (int i = tid; i < 4*TITLE*TITLE; i += 256) {
            int h2 = i / (TITLE*TITLE), rem = i % (TITLE*TITLE);
            int t = rem / TITLE, k2 = rem % TITLE;
            float s = 0.f;
            #pragma unroll
            for (int d0 = 0; d0 < 5; ++d0) {
                const uint2 qa = *(const uint2*)&qkvS[(0*32 + t)*100 + h2*24 + d0*4];
                const uint2 kb = *(const uint2*)&qkvS[(1*32 + k2)*100 + h2*24 + d0*4];
                float q0 = __uint_as_float(qa.x << 16);
                float q1 = __uint_as_float(qa.x & 0xffff0000u);
                float q2 = __uint_as_float(qa.y << 16);
                float q3 = __uint_as_float(qa.y & 0xffff0000u);
                float b0 = __uint_as_float(kb.x << 16);
                float b1 = __uint_as_float(kb.x & 0xffff0000u);
                float b2 = __uint_as_float(kb.y << 16);
                float b3 = __uint_as_float(kb.y & 0xffff0000u);
                s += q0*b0 + q1*b1 + q2*b2 + q3*b3;
            }
            scF[(h2*30 + t)*33 + k2] = s * 0.2236067977f;
        }
        __syncthreads();

        // ---- row softmax ----
        if (tid < 4*TITLE) {
            int h2 = tid / TITLE, t = tid % TITLE;
            float* row = &scF[(h2*30 + t)*33];
            float mx = -1e30f;
            for (int k2 = 0; k2 < TITLE; ++k2) mx = fmaxf(mx, row[k2]);
            float ss = 0.f;
            for (int k2 = 0; k2 < TITLE; ++k2) {
                float e = __expf(row[k2] - mx);
                row[k2] = e; ss += e;
            }
            float inv = 1.f / ss;
            for (int k2 = 0; k2 < TITLE; ++k2) row[k2] *= inv;
        }
        __syncthreads();

        // ---- out = att @ v ----
        for (int i = tid; i < 4*TITLE*DHD; i += 256) {
            int h2 = i / (TITLE*DHD), rem = i % (TITLE*DHD);
            int t = rem / DHD, dd = rem % DHD;
            float o = 0.f;
            for (int k2 = 0; k2 < TITLE; ++k2)
                o += scF[(h2*30 + t)*33 + k2] * bf2f(qkvS[(2*32 + k2)*100 + h2*24 + dd]);
            outS[t*424 + hg*80 + h2*20 + dd] = f2bf(o);
        }
        __syncthreads();
    }

    // ---- pooling scores via MFMA: [30x416]@[416x208] -> tanh * qp, row-sum ----
    for (int i = tid; i < 32*16; i += 256) poolP[i] = 0.f;
    __syncthreads();
    for (int tt = 0; tt < 4; ++tt) {
        int t = w * 4 + tt;
        if (t < 13) {
            const unsigned short* wb = wpT + (size_t)(t*16 + l15) * 416;
            f32x4 c0 = {0.f,0.f,0.f,0.f}, c1 = {0.f,0.f,0.f,0.f};
            #pragma unroll
            for (int ks = 0; ks < 13; ++ks) {
                bh8 a0 = *(const bh8*)&outS[l15*424 + ks*32 + g*8];
                bh8 a1 = *(const bh8*)&outS[(16+l15)*424 + ks*32 + g*8];
                bh8 b  = *(const bh8*)&wb[ks*32 + g*8];
                c0 = __builtin_amdgcn_mfma_f32_16x16x32_bf16(a0, b, c0, 0, 0, 0);
                c1 = __builtin_amdgcn_mfma_f32_16x16x32_bf16(a1, b, c1, 0, 0, 0);
            }
            int n = t*16 + l15;
            float qpn = (n < PP) ? qp[n] : 0.f;
            #pragma unroll
            for (int r = 0; r < 4; ++r) {
                float v0 = tanhf(c0[r]) * qpn;
                float v1 = tanhf(c1[r]) * qpn;
                #pragma unroll
                for (int mk = 1; mk < 16; mk <<= 1) {
                    v0 += __shfl_xor(v0, mk);
                    v1 += __shfl_xor(v1, mk);
                }
                if (l15 == 0) {
                    poolP[(g*4+r)*16 + t]    = v0;
                    poolP[(16+g*4+r)*16 + t] = v1;
                }
            }
        }
    }
    __syncthreads();
    if (tid < TITLE) {
        float s = 0.f;
        for (int t = 0; t < 13; ++t) s += poolP[tid*16 + t];
        alphaS[tid] = s;
    }
    __syncthreads();
    if (tid == 0) {
        float mx = -1e30f;
        for (int t = 0; t < TITLE; ++t) mx = fmaxf(mx, alphaS[t]);
        float ss = 0.f;
        for (int t = 0; t < TITLE; ++t) { float e = __expf(alphaS[t]-mx); alphaS[t] = e; ss += e; }
        float inv = 1.f / ss;
        for (int t = 0; t < TITLE; ++t) alphaS[t] *= inv;
    }
    __syncthreads();
    for (int dd = tid; dd < DD; dd += 256) {
        float a = 0.f;
        for (int t = 0; t < TITLE; ++t) a += alphaS[t] * bf2f(outS[t*424 + dd]);
        out_enc[(size_t)item*DD + dd] = a;
    }
}

// ---------------------------------------------------------------------------
// K2a: m = h @ W  ([N,400]@[400,400]); 8 rows per block
// ---------------------------------------------------------------------------
__global__ __launch_bounds__(256) void mm_nodes(
    const float* __restrict__ A, const float* __restrict__ W, float* __restrict__ Mo)
{
    __shared__ float a[8][DD];
    const int r0 = blockIdx.x * 8, tid = threadIdx.x;
    for (int i = tid; i < 8*DD; i += 256)
        a[i/DD][i%DD] = A[(size_t)(r0 + i/DD)*DD + i%DD];
    __syncthreads();
    for (int d = tid; d < DD; d += 256) {
        float acc[8] = {0,0,0,0,0,0,0,0};
        for (int k4 = 0; k4 < 100; ++k4) {
            float w0 = W[(size_t)(k4*4+0)*DD + d];
            float w1 = W[(size_t)(k4*4+1)*DD + d];
            float w2 = W[(size_t)(k4*4+2)*DD + d];
            float w3 = W[(size_t)(k4*4+3)*DD + d];
            #pragma unroll
            for (int r = 0; r < 8; ++r) {
                const float4 av = *(const float4*)&a[r][k4*4];
                acc[r] += av.x*w0 + av.y*w1 + av.z*w2 + av.w*w3;
            }
        }
        #pragma unroll
        for (int r = 0; r < 8; ++r) Mo[(size_t)(r0+r)*DD + d] = acc[r];
    }
}

// ---------------------------------------------------------------------------
// CSR build: count -> exclusive scan -> cursor scatter
// ---------------------------------------------------------------------------
__global__ __launch_bounds__(256) void count_edges(
    const int* __restrict__ ei, int* __restrict__ cnt)
{
    int e = blockIdx.x * 256 + threadIdx.x;
    if (e < EE) atomicAdd(&cnt[ei[EE + e]], 1);
}

__global__ __launch_bounds__(256) void build_offsets(
    const int* __restrict__ cnt, int* __restrict__ off, int* __restrict__ cursor)
{
    __shared__ int csum[256];
    const int tid = threadIdx.x;
    const int chunk = (NN + 255) / 256;   // 40
    int s = 0;
    for (int i = 0; i < chunk; ++i) {
        int idx = tid * chunk + i;
        if (idx < NN) s += cnt[idx];
    }
    csum[tid] = s;
    __syncthreads();
    if (tid == 0) {
        int run = 0;
        for (int i = 0; i < 256; ++i) { int c = csum[i]; csum[i] = run; run += c; }
    }
    __syncthreads();
    int run = csum[tid];
    for (int i = 0; i < chunk; ++i) {
        int idx = tid * chunk + i;
        if (idx < NN) {
            off[idx] = run; cursor[idx] = run;
            run += cnt[idx];
        }
    }
}

__global__ __launch_bounds__(256) void fill_csr(
    const int* __restrict__ ei, int* __restrict__ cursor, int* __restrict__ srclist)
{
    int e = blockIdx.x * 256 + threadIdx.x;
    if (e < EE) {
        int d = ei[EE + e];
        int pos = atomicAdd(&cursor[d], 1);
        srclist[pos] = ei[e];
    }
}

// ---------------------------------------------------------------------------
// K2b: agg[node] = sum over incoming edges of m[src]
// ---------------------------------------------------------------------------
__global__ __launch_bounds__(256) void gather_agg(
    const float* __restrict__ m, const int* __restrict__ off,
    const int* __restrict__ cnt, const int* __restrict__ srclist,
    float* __restrict__ agg)
{
    __shared__ int sl[128];
    const int node = blockIdx.x, tid = threadIdx.x;
    const int o0 = off[node], deg = cnt[node];
    float acc0 = 0.f, acc1 = 0.f;
    const int d0 = tid, d1 = tid + 256;
    for (int j0 = 0; j0 < deg; j0 += 128) {
        if (tid < 128 && j0 + tid < deg) sl[tid] = srclist[o0 + j0 + tid];
        __syncthreads();
        const int jn = (deg - j0 < 128) ? (deg - j0) : 128;
        for (int j = 0; j < jn; ++j) {
            const float* mr = &m[(size_t)sl[j] * DD];
            acc0 += mr[d0];
            if (d1 < DD) acc1 += mr[d1];
        }
        __syncthreads();
    }
    agg[(size_t)node * DD + d0] = acc0;
    if (d1 < DD) agg[(size_t)node * DD + d1] = acc1;
}

// ---------------------------------------------------------------------------
// K2c: fused GRU cell; 8 rows per block.
// ---------------------------------------------------------------------------
__global__ __launch_bounds__(256) void gru_step(
    const float* __restrict__ agg, const float* __restrict__ hin,
    const float* __restrict__ wih, const float* __restrict__ whh,
    const float* __restrict__ bih, const float* __restrict__ bhh,
    float* __restrict__ hout)
{
    __shared__ float al[8][DD], hl[8][DD];
    const int r0 = blockIdx.x * 8, tid = threadIdx.x;
    for (int i = tid; i < 8*DD; i += 256) {
        int r = i/DD, k = i%DD;
        al[r][k] = agg[(size_t)(r0+r)*DD + k];
        hl[r][k] = hin[(size_t)(r0+r)*DD + k];
    }
    __syncthreads();
    for (int d = tid; d < DD; d += 256) {
        float air[8]={0,0,0,0,0,0,0,0}, aiz[8]={0,0,0,0,0,0,0,0}, ain[8]={0,0,0,0,0,0,0,0};
        float ahr[8]={0,0,0,0,0,0,0,0}, ahz[8]={0,0,0,0,0,0,0,0}, ahn[8]={0,0,0,0,0,0,0,0};
        for (int k = 0; k < DD; ++k) {
            const float* wi = &wih[(size_t)k*1200 + d];
            float wir = wi[0], wiz = wi[400], win = wi[800];
            const float* wh = &whh[(size_t)k*1200 + d];
            float whr = wh[0], whz = wh[400], whn = wh[800];
            #pragma unroll
            for (int r = 0; r < 8; ++r) {
                float a = al[r][k], hh = hl[r][k];
                air[r] += a*wir; aiz[r] += a*wiz; ain[r] += a*win;
                ahr[r] += hh*whr; ahz[r] += hh*whz; ahn[r] += hh*whn;
            }
        }
        float bir = bih[d], biz = bih[d+400], bin = bih[d+800];
        float bhr = bhh[d], bhz = bhh[d+400], bhn = bhh[d+800];
        #pragma unroll
        for (int r = 0; r < 8; ++r) {
            float rg = 1.f/(1.f + __expf(-(air[r]+bir + ahr[r]+bhr)));
            float zg = 1.f/(1.f + __expf(-(aiz[r]+biz + ahz[r]+bhz)));
            float ng = tanhf(ain[r]+bin + rg*(ahn[r]+bhn));
            hout[(size_t)(r0+r)*DD + d] = (1.f-zg)*ng + zg*hl[r][d];
        }
    }
}

// ---------------------------------------------------------------------------
// K3a: clicked_total = concat(x_enc[midx], h[midx])*mask @ w_click + b_click
// ---------------------------------------------------------------------------
__global__ __launch_bounds__(256) void clicked_mm(
    const int* __restrict__ map, const float* __restrict__ xe,
    const float* __restrict__ hg, const float* __restrict__ wc,
    const float* __restrict__ bc, float* __restrict__ ct)
{
    __shared__ float a[8][2*DD];
    const int r0 = blockIdx.x * 8, tid = threadIdx.x;
    for (int i = tid; i < 8*2*DD; i += 256) {
        int r = i/(2*DD), k = i%(2*DD);
        int mi = map[r0 + r];
        float v = 0.f;
        if (mi >= 0) v = (k < DD) ? xe[(size_t)mi*DD + k] : hg[(size_t)mi*DD + (k-DD)];
        a[r][k] = v;
    }
    __syncthreads();
    for (int d = tid; d < DD; d += 256) {
        float acc[8] = {0,0,0,0,0,0,0,0};
        for (int k = 0; k < 2*DD; ++k) {
            float w = wc[(size_t)k*DD + d];
            #pragma unroll
            for (int r = 0; r < 8; ++r) acc[r] += a[r][k]*w;
        }
        float bb = bc[d];
        #pragma unroll
        for (int r = 0; r < 8; ++r) ct[(size_t)(r0+r)*DD + d] = acc[r] + bb;
    }
}

// ---------------------------------------------------------------------------
// K3b: uq/uk/uv = ct @ u_wq/u_wk/u_wv
// ---------------------------------------------------------------------------
__global__ __launch_bounds__(256) void user_qkv(
    const float* __restrict__ ct,
    const float* __restrict__ wq, const float* __restrict__ wk, const float* __restrict__ wv,
    float* __restrict__ uq, float* __restrict__ uk, float* __restrict__ uv)
{
    __shared__ float a[8][DD];
    const int r0 = blockIdx.x * 8, tid = threadIdx.x;
    for (int i = tid; i < 8*DD; i += 256)
        a[i/DD][i%DD] = ct[(size_t)(r0 + i/DD)*DD + i%DD];
    __syncthreads();
    for (int d = tid; d < DD; d += 256) {
        float aq[8]={0,0,0,0,0,0,0,0}, ak[8]={0,0,0,0,0,0,0,0}, av[8]={0,0,0,0,0,0,0,0};
        for (int k = 0; k < DD; ++k) {
            float wq_ = wq[(size_t)k*DD + d];
            float wk_ = wk[(size_t)k*DD + d];
            float wv_ = wv[(size_t)k*DD + d];
            #pragma unroll
            for (int r = 0; r < 8; ++r) {
                float x = a[r][k];
                aq[r] += x*wq_; ak[r] += x*wk_; av[r] += x*wv_;
            }
        }
        #pragma unroll
        for (int r = 0; r < 8; ++r) {
            uq[(size_t)(r0+r)*DD + d] = aq[r];
            uk[(size_t)(r0+r)*DD + d] = ak[r];
            uv[(size_t)(r0+r)*DD + d] = av[r];
        }
    }
}

// ---------------------------------------------------------------------------
// K3c: masked MHSA per (batch, head); block = 64 threads
// ---------------------------------------------------------------------------
__global__ __launch_bounds__(64) void user_attn(
    const float* __restrict__ uq, const float* __restrict__ uk,
    const float* __restrict__ uv, const int* __restrict__ map,
    float* __restrict__ uo)
{
    const int b = blockIdx.x / HH, h = blockIdx.x % HH, tid = threadIdx.x;
    __shared__ float q[NCK][DHD], k[NCK][DHD], v[NCK][DHD];
    __shared__ float sc[NCK][NCK+2];
    __shared__ float biasl[NCK];
    for (int i = tid; i < NCK*DHD; i += 64) {
        int c = i/DHD, d = i%DHD;
        size_t base = ((size_t)b*NCK + c)*DD + h*DHD + d;
        q[c][d] = uq[base]; k[c][d] = uk[base]; v[c][d] = uv[base];
    }
    for (int i = tid; i < NCK; i += 64)
        biasl[i] = (map[b*NCK + i] >= 0) ? 0.f : -1e9f;
    __syncthreads();
    for (int i = tid; i < NCK*NCK; i += 64) {
        int t = i/NCK, k2 = i%NCK;
        float s = 0.f;
        #pragma unroll
        for (int d4 = 0; d4 < 5; ++d4) {
            const float4 qa = *(const float4*)&q[t][d4*4];
            const float4 kb = *(const float4*)&k[k2][d4*4];
            s += qa.x*kb.x + qa.y*kb.y + qa.z*kb.z + qa.w*kb.w;
        }
        sc[t][k2] = s * 0.2236067977f + biasl[k2];
    }
    __syncthreads();
    if (tid < NCK) {
        float mx = -1e30f;
        for (int k2 = 0; k2 < NCK; ++k2) mx = fmaxf(mx, sc[tid][k2]);
        float ssum = 0.f;
        for (int k2 = 0; k2 < NCK; ++k2) { float e = __expf(sc[tid][k2]-mx); sc[tid][k2] = e; ssum += e; }
        float inv = 1.f/ssum;
        for (int k2 = 0; k2 < NCK; ++k2) sc[tid][k2] *= inv;
    }
    __syncthreads();
    for (int i = tid; i < NCK*DHD; i += 64) {
        int t = i/DHD, d = i%DHD;
        float o = 0.f;
        for (int k2 = 0; k2 < NCK; ++k2) o += sc[t][k2]*v[k2][d];
        uo[((size_t)b*NCK + t)*DD + h*DHD + d] = o;
    }
}

// ---------------------------------------------------------------------------
// K3d: masked attention pooling -> user_emb[b][400]; block per batch
// ---------------------------------------------------------------------------
__global__ __launch_bounds__(256) void user_pool(
    const float* __restrict__ uo, const int* __restrict__ map,
    const float* __restrict__ uwp, const float* __restrict__ uqp,
    float* __restrict__ user_emb)
{
    const int b = blockIdx.x, tid = threadIdx.x;
    __shared__ float alpha[64];
    __shared__ float red[256];
    for (int t = 0; t < NCK; ++t) {
        float partial = 0.f;
        const float* ur = uo + ((size_t)b*NCK + t)*DD;
        for (int p = tid; p < PP; p += 256) {
            float s = 0.f;
            for (int d = 0; d < DD; ++d) s += ur[d] * uwp[(size_t)d*PP + p];
            partial += tanhf(s) * uqp[p];
        }
        red[tid] = partial; __syncthreads();
        for (int st = 128; st > 0; st >>= 1) {
            if (tid < st) red[tid] += red[tid+st];
            __syncthreads();
        }
        if (tid == 0)
            alpha[t] = red[0] + ((map[b*NCK + t] >= 0) ? 0.f : -1e9f);
        __syncthreads();
    }
    if (tid == 0) {
        float mx = -1e30f;
        for (int t = 0; t < NCK; ++t) mx = fmaxf(mx, alpha[t]);
        float ssum = 0.f;
        for (int t = 0; t < NCK; ++t) { float e = __expf(alpha[t]-mx); alpha[t] = e; ssum += e; }
        float inv = 1.f/ssum;
        for (int t = 0; t < NCK; ++t) alpha[t] *= inv;
    }
    __syncthreads();
    for (int d = tid; d < DD; d += 256) {
        float acc = 0.f;
        for (int t = 0; t < NCK; ++t) acc += alpha[t] * uo[((size_t)b*NCK + t)*DD + d];
        user_emb[(size_t)b*DD + d] = acc;
    }
}

// ---------------------------------------------------------------------------
// K5: candidate scoring + NCE loss; single block
// ---------------------------------------------------------------------------
__global__ __launch_bounds__(256) void score_loss(
    const float* __restrict__ cr, const float* __restrict__ cf,
    const float* __restrict__ ue, const int* __restrict__ label,
    float* __restrict__ dout)
{
    __shared__ float sr[BB][NCAND], sf[BB][NCAND], red[BB];
    const int tid = threadIdx.x;
    for (int i = tid; i < 2*BB*NCAND; i += 256) {
        int which = i / (BB*NCAND);
        int r = i % (BB*NCAND);
        int b = r / NCAND, c = r % NCAND;
        const float* ce = (which ? cf : cr) + (size_t)r*DD;
        const float* u = ue + (size_t)b*DD;
        float s = 0.f;
        for (int d = 0; d < DD; ++d) s += ce[d]*u[d];
        if (which) sf[b][c] = s; else sr[b][c] = s;
        dout[1 + i] = s;
    }
    __syncthreads();
    if (tid < BB) {
        int b = tid;
        float mr = -1e30f, mf = -1e30f;
        for (int c = 0; c < NCAND; ++c) { mr = fmaxf(mr, sr[b][c]); mf = fmaxf(mf, sf[b][c]); }
        float er = 0.f, ef = 0.f;
        for (int c = 0; c < NCAND; ++c) { er += expf(sr[b][c]-mr); ef += expf(sf[b][c]-mf); }
        float lser = logf(er)+mr, lsef = logf(ef)+mf;
        int lab = label[b]; lab = lab < 0 ? 0 : (lab > NCAND-1 ? NCAND-1 : lab);
        float crb = lser - sr[b][lab];
        float cfb = 0.f;
        for (int c = 0; c < NCAND; ++c) cfb += (lsef - sf[b][c]);
        red[tid] = crb + 0.5f * (cfb / (float)NCAND);
    }
    __syncthreads();
    if (tid == 0) {
        float L = 0.f;
        for (int b = 0; b < BB; ++b) L += red[b];
        dout[0] = L / (float)BB;
    }
}

// ---------------------------------------------------------------------------
extern "C" void kernel_launch(void* const* d_in, const int* in_sizes, int n_in,
                              void* d_out, int out_size, void* d_ws, size_t ws_size,
                              hipStream_t stream) {
    (void)in_sizes; (void)n_in; (void)out_size; (void)ws_size;
    const int*   sub_x  = (const int*)d_in[0];
    const int*   edge   = (const int*)d_in[1];
    const int*   mapi   = (const int*)d_in[2];
    const int*   cand   = (const int*)d_in[3];
    const int*   fcand  = (const int*)d_in[4];
    const int*   label  = (const int*)d_in[5];
    const float* glove  = (const float*)d_in[6];
    const float* nwq    = (const float*)d_in[7];
    const float* nwk    = (const float*)d_in[8];
    const float* nwv    = (const float*)d_in[9];
    const float* nwp    = (const float*)d_in[10];
    const float* nqp    = (const float*)d_in[11];
    const float* ggc    = (const float*)d_in[12];
    const float* wih    = (const float*)d_in[13];
    const float* whh    = (const float*)d_in[14];
    const float* bih    = (const float*)d_in[15];
    const float* bhh    = (const float*)d_in[16];
    const float* wclick = (const float*)d_in[17];
    const float* bclick = (const float*)d_in[18];
    const float* uwq    = (const float*)d_in[19];
    const float* uwk    = (const float*)d_in[20];
    const float* uwv    = (const float*)d_in[21];
    const float* uwp    = (const float*)d_in[22];
    const float* uqp    = (const float*)d_in[23];

    // workspace layout (floats); ws_size = 256 MB
    float* ws     = (float*)d_ws;
    float* x_enc  = ws;                       // 4,000,000 f
    float* hbuf   = ws + 4000000;             // 4,000,000 f
    float* region = ws + 8000000;             // 8,000,000 f shared region
    float* mbuf   = region;                   // GGC: m
    float* aggbuf = region + 4000000;         // GGC: agg
    // after GGC, region reused:
    float* ct   = region;                     // 1,280,000
    float* uq   = region + 1280000;
    float* uk   = region + 2560000;
    float* uv   = region + 3840000;
    float* uo   = region + 5120000;           // 1,280,000
    float* user = region + 6400000;           // 25,600
    float* crnc = region + 6425600;           // 128,000
    float* cfnc = region + 6553600;           // 128,000
    // int area at byte offset 64 MB (float offset 16,777,216 .. ~17,007,216)
    int* ibase   = (int*)((char*)d_ws + (size_t)64*1024*1024);
    int* cnt     = ibase;                     // 10,000
    int* off     = ibase + 10000;             // 10,000
    int* cursor  = ibase + 20000;             // 10,000
    int* srclist = ibase + 30000;             // 200,000
    // bf16 prepped weights, beyond int area
    unsigned short* Wt  = (unsigned short*)(ws + 17100000);  // 1200*320 shorts
    unsigned short* wpT = (unsigned short*)(ws + 17300000);  // 208*416 shorts

    // 0) prep transposed bf16 weights (tiny; L2-resident afterwards)
    prep_wt<<<1500, 256, 0, stream>>>(nwq, nwk, nwv, Wt);
    prep_wpt<<<338, 256, 0, stream>>>(nwp, wpT);

    // 1) encode all nodes
    news_enc<<<NN, 256, 0, stream>>>(sub_x, TOKS, glove, Wt, wpT, nqp, x_enc);

    // 1b) build CSR-by-destination once (reused by all 3 GGC layers)
    hipMemsetAsync(cnt, 0, NN*sizeof(int), stream);
    count_edges<<<(EE+255)/256, 256, 0, stream>>>(edge, cnt);
    build_offsets<<<1, 256, 0, stream>>>(cnt, off, cursor);
    fill_csr<<<(EE+255)/256, 256, 0, stream>>>(edge, cursor, srclist);

    // 2) GatedGraphConv x3 (gather instead of atomic scatter)
    const float* hin = x_enc;
    for (int l = 0; l < 3; ++l) {
        mm_nodes<<<NN/8, 256, 0, stream>>>(hin, ggc + (size_t)l*DD*DD, mbuf);
        gather_agg<<<NN, 256, 0, stream>>>(mbuf, off, cnt, srclist, aggbuf);
        gru_step<<<NN/8, 256, 0, stream>>>(aggbuf, hin, wih, whh, bih, bhh, hbuf);
        hin = hbuf;
    }

    // 3) click + user encoder
    clicked_mm<<<(BB*NCK)/8, 256, 0, stream>>>(mapi, x_enc, hbuf, wclick, bclick, ct);
    user_qkv<<<(BB*NCK)/8, 256, 0, stream>>>(ct, uwq, uwk, uwv, uq, uk, uv);
    user_attn<<<BB*HH, 64, 0, stream>>>(uq, uk, uv, mapi, uo);
    user_pool<<<BB, 256, 0, stream>>>(uo, mapi, uwp, uqp, user);

    // 4) candidates
    news_enc<<<BB*NCAND, 256, 0, stream>>>(cand,  TOKS, glove, Wt, wpT, nqp, crnc);
    news_enc<<<BB*NCAND, 256, 0, stream>>>(fcand, TOKS, glove, Wt, wpT, nqp, cfnc);

    // 5) scores + loss
    score_loss<<<1, 256, 0, stream>>>(crnc, cfnc, user, label, (float*)d_out);
}

// Round 6
// 4639.994 us; speedup vs baseline: 79.1647x; 1.0979x over previous
//
#include <hip/hip_runtime.h>
#include <cmath>

#define NN 10000
#define EE 200000
#define BB 64
#define NCK 50
#define NCAND 5
#define TOKS 38
#define TITLE 30
#define GDIM 300
#define HH 20
#define DHD 20
#define DD 400
#define PP 200

typedef __attribute__((ext_vector_type(8))) short bh8;
typedef __attribute__((ext_vector_type(4))) float f32x4;

__device__ __forceinline__ float bf2f(unsigned short u) {
    return __uint_as_float(((unsigned int)u) << 16);
}
__device__ __forceinline__ unsigned short f2bf(float f) {
    unsigned int u = __float_as_uint(f);
    u += 0x7fffu + ((u >> 16) & 1u);
    return (unsigned short)(u >> 16);
}

// ---------------------------------------------------------------------------
// prep: Wt[1200][320] bf16 = concat(wq,wk,wv) transposed, k-padded with zeros
// ---------------------------------------------------------------------------
__global__ __launch_bounds__(256) void prep_wt(
    const float* __restrict__ wq, const float* __restrict__ wk,
    const float* __restrict__ wv, unsigned short* __restrict__ Wt)
{
    int i = blockIdx.x * 256 + threadIdx.x;
    if (i >= 1200 * 320) return;
    int n = i / 320, k = i % 320;
    int m = n / 400, nn = n % 400;
    const float* W = (m == 0) ? wq : ((m == 1) ? wk : wv);
    float v = (k < GDIM) ? W[(size_t)k * DD + nn] : 0.f;
    Wt[i] = f2bf(v);
}

// prep: wpT[208][416] bf16 = wp[400][200] transposed, padded with zeros
__global__ __launch_bounds__(256) void prep_wpt(
    const float* __restrict__ wp, unsigned short* __restrict__ wpT)
{
    int i = blockIdx.x * 256 + threadIdx.x;
    if (i >= 208 * 416) return;
    int n = i / 416, k = i % 416;
    float v = (n < PP && k < DD) ? wp[(size_t)k * PP + n] : 0.f;
    wpT[i] = f2bf(v);
}

// ---------------------------------------------------------------------------
// K1: fused news encoder — MFMA QKV + MFMA attention (wave-per-head) +
// MFMA pooling. One block (256 thr = 4 waves) per item. LDS ~62KB.
// Frag maps (HW-verified r5): A/B row-major [row|col][k] with k-slot
// (lane>>4)*8+j; C/D col=lane&15, row=(lane>>4)*4+reg.
// ---------------------------------------------------------------------------
__global__ __launch_bounds__(256) void news_enc(
    const int* __restrict__ tokens, int tok_stride,
    const float* __restrict__ glove,
    const unsigned short* __restrict__ Wt,     // [1200][320] bf16
    const unsigned short* __restrict__ wpT,    // [208][416] bf16
    const float* __restrict__ qp,
    float* __restrict__ out_enc)
{
    // union: embS [32][328] bf16 (20992B)  |  qS/kS/vT [4][32][32] bf16 (24576B)
    __shared__ __align__(16) unsigned char uS[24576];
    __shared__ __align__(16) unsigned short pS[4 * 32 * 32];   // 8192B
    __shared__ __align__(16) unsigned short outS[32 * 424];    // 27136B
    __shared__ float poolP[32][16];
    __shared__ int   tokS[32];
    __shared__ float alphaS[32];

    unsigned short* embS = (unsigned short*)uS;      // [32][328]
    unsigned short* qS   = (unsigned short*)uS;      // [4][32][32]
    unsigned short* kS   = qS + 4*32*32;
    unsigned short* vT   = kS + 4*32*32;

    const int tid  = threadIdx.x;
    const int item = blockIdx.x;
    const int w    = tid >> 6;        // wave 0..3
    const int lane = tid & 63;
    const int g    = lane >> 4;       // k-group 0..3
    const int l15  = lane & 15;

    if (tid < TITLE) tokS[tid] = tokens[(size_t)item * tok_stride + tid];
    for (int i = tid; i < (32*328)/2; i += 256) ((unsigned int*)embS)[i] = 0u;
    for (int i = tid; i < (32*424)/2; i += 256) ((unsigned int*)outS)[i] = 0u;
    __syncthreads();

    // gather glove rows -> embS bf16
    for (int i = tid; i < TITLE * 75; i += 256) {
        int t = i / 75, g4 = i % 75;
        const float4 v = *(const float4*)&glove[(size_t)tokS[t] * GDIM + g4 * 4];
        embS[t*328 + g4*4+0] = f2bf(v.x);
        embS[t*328 + g4*4+1] = f2bf(v.y);
        embS[t*328 + g4*4+2] = f2bf(v.z);
        embS[t*328 + g4*4+3] = f2bf(v.w);
    }
    __syncthreads();

    // preload A-fragments (emb rows): 2 m-tiles x 10 k-steps (80 VGPR)
    bh8 afr[2][10];
    #pragma unroll
    for (int mt = 0; mt < 2; ++mt)
        #pragma unroll
        for (int ks = 0; ks < 10; ++ks)
            afr[mt][ks] = *(const bh8*)&embS[(mt*16 + l15)*328 + ks*32 + g*8];
    __syncthreads();   // all waves done with embS -> union reusable

    // zero k-pads of qS/kS (k 20..31, all rows) and vT rows d=20..31
    for (int i = tid; i < 4*32*12; i += 256) {
        int h2 = i / (32*12), rem = i % (32*12);
        int row = rem / 12, kk = 20 + rem % 12;
        qS[(h2*32 + row)*32 + kk] = 0;
        kS[(h2*32 + row)*32 + kk] = 0;
        vT[(h2*32 + (kk))*32 + row] = 0;   // rows 20..31 of vT, all cols
    }
    __syncthreads();

    const float sc = 0.2236067977f;

    for (int hg = 0; hg < 5; ++hg) {
        // ---- QKV via MFMA: 15 n-tiles (q|k|v x 5) over 4 waves ----
        for (int tt = 0; tt < 4; ++tt) {
            int t = w * 4 + tt;
            if (t < 15) {
                int m = t / 5, loc = t % 5;
                const unsigned short* wb =
                    Wt + (size_t)(m*400 + hg*80 + loc*16 + l15) * 320;
                f32x4 c0 = {0.f,0.f,0.f,0.f}, c1 = {0.f,0.f,0.f,0.f};
                #pragma unroll
                for (int ks = 0; ks < 10; ++ks) {
                    bh8 b = *(const bh8*)&wb[ks*32 + g*8];
                    c0 = __builtin_amdgcn_mfma_f32_16x16x32_bf16(afr[0][ks], b, c0, 0, 0, 0);
                    c1 = __builtin_amdgcn_mfma_f32_16x16x32_bf16(afr[1][ks], b, c1, 0, 0, 0);
                }
                int c2 = loc*16 + l15, h2 = c2 / 20, dloc = c2 % 20;
                #pragma unroll
                for (int r = 0; r < 4; ++r) {
                    int row0 = g*4 + r, row1 = 16 + g*4 + r;
                    if (m == 0) {
                        qS[(h2*32 + row0)*32 + dloc] = f2bf(c0[r]);
                        qS[(h2*32 + row1)*32 + dloc] = f2bf(c1[r]);
                    } else if (m == 1) {
                        kS[(h2*32 + row0)*32 + dloc] = f2bf(c0[r]);
                        kS[(h2*32 + row1)*32 + dloc] = f2bf(c1[r]);
                    } else {
                        vT[(h2*32 + dloc)*32 + row0] = f2bf(c0[r]);
                        vT[(h2*32 + dloc)*32 + row1] = f2bf(c1[r]);
                    }
                }
            }
        }
        __syncthreads();

        // ---- attention, one wave per head ----
        {
            const int h = w;
            const unsigned short* qh = qS + h*32*32;
            const unsigned short* kh = kS + h*32*32;
            bh8 a0 = *(const bh8*)&qh[l15*32 + g*8];
            bh8 a1 = *(const bh8*)&qh[(16+l15)*32 + g*8];
            bh8 b0 = *(const bh8*)&kh[l15*32 + g*8];
            bh8 b1 = *(const bh8*)&kh[(16+l15)*32 + g*8];
            f32x4 s00 = {0.f,0.f,0.f,0.f}, s01 = {0.f,0.f,0.f,0.f};
            f32x4 s10 = {0.f,0.f,0.f,0.f}, s11 = {0.f,0.f,0.f,0.f};
            s00 = __builtin_amdgcn_mfma_f32_16x16x32_bf16(a0, b0, s00, 0, 0, 0);
            s01 = __builtin_amdgcn_mfma_f32_16x16x32_bf16(a0, b1, s01, 0, 0, 0);
            s10 = __builtin_amdgcn_mfma_f32_16x16x32_bf16(a1, b0, s10, 0, 0, 0);
            s11 = __builtin_amdgcn_mfma_f32_16x16x32_bf16(a1, b1, s11, 0, 0, 0);
            const float maskv = (l15 >= 14) ? -1e30f : 0.f;   // key cols >=30
            unsigned short* ph = pS + h*32*32;
            #pragma unroll
            for (int r = 0; r < 4; ++r) {
                // m-tile 0 (query rows g*4+r)
                {
                    float v0 = s00[r]*sc, v1 = s01[r]*sc + maskv;
                    float mx = fmaxf(v0, v1);
                    #pragma unroll
                    for (int mk = 1; mk < 16; mk <<= 1) mx = fmaxf(mx, __shfl_xor(mx, mk));
                    float e0 = __expf(v0 - mx), e1 = __expf(v1 - mx);
                    float ssum = e0 + e1;
                    #pragma unroll
                    for (int mk = 1; mk < 16; mk <<= 1) ssum += __shfl_xor(ssum, mk);
                    float inv = 1.f / ssum;
                    ph[(g*4+r)*32 + l15]      = f2bf(e0*inv);
                    ph[(g*4+r)*32 + 16 + l15] = f2bf(e1*inv);
                }
                // m-tile 1 (query rows 16+g*4+r)
                {
                    float v0 = s10[r]*sc, v1 = s11[r]*sc + maskv;
                    float mx = fmaxf(v0, v1);
                    #pragma unroll
                    for (int mk = 1; mk < 16; mk <<= 1) mx = fmaxf(mx, __shfl_xor(mx, mk));
                    float e0 = __expf(v0 - mx), e1 = __expf(v1 - mx);
                    float ssum = e0 + e1;
                    #pragma unroll
                    for (int mk = 1; mk < 16; mk <<= 1) ssum += __shfl_xor(ssum, mk);
                    float inv = 1.f / ssum;
                    ph[(16+g*4+r)*32 + l15]      = f2bf(e0*inv);
                    ph[(16+g*4+r)*32 + 16 + l15] = f2bf(e1*inv);
                }
            }
        }
        __syncthreads();

        // ---- PV via MFMA + writeback ----
        {
            const int h = w;
            const unsigned short* ph = pS + h*32*32;
            const unsigned short* vh = vT + h*32*32;
            bh8 pa0 = *(const bh8*)&ph[l15*32 + g*8];
            bh8 pa1 = *(const bh8*)&ph[(16+l15)*32 + g*8];
            bh8 vb0 = *(const bh8*)&vh[l15*32 + g*8];
            bh8 vb1 = *(const bh8*)&vh[(16+l15)*32 + g*8];
            f32x4 o00 = {0.f,0.f,0.f,0.f}, o01 = {0.f,0.f,0.f,0.f};
            f32x4 o10 = {0.f,0.f,0.f,0.f}, o11 = {0.f,0.f,0.f,0.f};
            o00 = __builtin_amdgcn_mfma_f32_16x16x32_bf16(pa0, vb0, o00, 0, 0, 0);
            o01 = __builtin_amdgcn_mfma_f32_16x16x32_bf16(pa0, vb1, o01, 0, 0, 0);
            o10 = __builtin_amdgcn_mfma_f32_16x16x32_bf16(pa1, vb0, o10, 0, 0, 0);
            o11 = __builtin_amdgcn_mfma_f32_16x16x32_bf16(pa1, vb1, o11, 0, 0, 0);
            int base = hg*80 + h*20;
            #pragma unroll
            for (int r = 0; r < 4; ++r) {
                int row0 = g*4 + r, row1 = 16 + g*4 + r;
                outS[row0*424 + base + l15] = f2bf(o00[r]);
                if (l15 < 4) outS[row0*424 + base + 16 + l15] = f2bf(o01[r]);
                if (row1 < TITLE) {
                    outS[row1*424 + base + l15] = f2bf(o10[r]);
                    if (l15 < 4) outS[row1*424 + base + 16 + l15] = f2bf(o11[r]);
                }
            }
        }
        __syncthreads();
    }

    // ---- pooling scores via MFMA: [30x416]@[416x208] -> tanh * qp, row-sum ----
    for (int i = tid; i < 32*16; i += 256) poolP[i/16][i%16] = 0.f;
    __syncthreads();
    for (int tt = 0; tt < 4; ++tt) {
        int t = w * 4 + tt;
        if (t < 13) {
            const unsigned short* wb = wpT + (size_t)(t*16 + l15) * 416;
            f32x4 c0 = {0.f,0.f,0.f,0.f}, c1 = {0.f,0.f,0.f,0.f};
            #pragma unroll
            for (int ks = 0; ks < 13; ++ks) {
                bh8 a0 = *(const bh8*)&outS[l15*424 + ks*32 + g*8];
                bh8 a1 = *(const bh8*)&outS[(16+l15)*424 + ks*32 + g*8];
                bh8 b  = *(const bh8*)&wb[ks*32 + g*8];
                c0 = __builtin_amdgcn_mfma_f32_16x16x32_bf16(a0, b, c0, 0, 0, 0);
                c1 = __builtin_amdgcn_mfma_f32_16x16x32_bf16(a1, b, c1, 0, 0, 0);
            }
            int n = t*16 + l15;
            float qpn = (n < PP) ? qp[n] : 0.f;
            #pragma unroll
            for (int r = 0; r < 4; ++r) {
                float v0 = tanhf(c0[r]) * qpn;
                float v1 = tanhf(c1[r]) * qpn;
                #pragma unroll
                for (int mk = 1; mk < 16; mk <<= 1) {
                    v0 += __shfl_xor(v0, mk);
                    v1 += __shfl_xor(v1, mk);
                }
                if (l15 == 0) {
                    poolP[g*4+r][t]    = v0;
                    poolP[16+g*4+r][t] = v1;
                }
            }
        }
    }
    __syncthreads();
    if (tid < TITLE) {
        float s = 0.f;
        for (int t = 0; t < 13; ++t) s += poolP[tid][t];
        alphaS[tid] = s;
    }
    __syncthreads();
    if (tid == 0) {
        float mx = -1e30f;
        for (int t = 0; t < TITLE; ++t) mx = fmaxf(mx, alphaS[t]);
        float ss = 0.f;
        for (int t = 0; t < TITLE; ++t) { float e = __expf(alphaS[t]-mx); alphaS[t] = e; ss += e; }
        float inv = 1.f / ss;
        for (int t = 0; t < TITLE; ++t) alphaS[t] *= inv;
    }
    __syncthreads();
    for (int dd = tid; dd < DD; dd += 256) {
        float a = 0.f;
        for (int t = 0; t < TITLE; ++t) a += alphaS[t] * bf2f(outS[t*424 + dd]);
        out_enc[(size_t)item*DD + dd] = a;
    }
}

// ---------------------------------------------------------------------------
// K2a: m = h @ W  ([N,400]@[400,400]); 8 rows per block
// ---------------------------------------------------------------------------
__global__ __launch_bounds__(256) void mm_nodes(
    const float* __restrict__ A, const float* __restrict__ W, float* __restrict__ Mo)
{
    __shared__ float a[8][DD];
    const int r0 = blockIdx.x * 8, tid = threadIdx.x;
    for (int i = tid; i < 8*DD; i += 256)
        a[i/DD][i%DD] = A[(size_t)(r0 + i/DD)*DD + i%DD];
    __syncthreads();
    for (int d = tid; d < DD; d += 256) {
        float acc[8] = {0,0,0,0,0,0,0,0};
        for (int k4 = 0; k4 < 100; ++k4) {
            float w0 = W[(size_t)(k4*4+0)*DD + d];
            float w1 = W[(size_t)(k4*4+1)*DD + d];
            float w2 = W[(size_t)(k4*4+2)*DD + d];
            float w3 = W[(size_t)(k4*4+3)*DD + d];
            #pragma unroll
            for (int r = 0; r < 8; ++r) {
                const float4 av = *(const float4*)&a[r][k4*4];
                acc[r] += av.x*w0 + av.y*w1 + av.z*w2 + av.w*w3;
            }
        }
        #pragma unroll
        for (int r = 0; r < 8; ++r) Mo[(size_t)(r0+r)*DD + d] = acc[r];
    }
}

// ---------------------------------------------------------------------------
// CSR build: count -> exclusive scan -> cursor scatter
// ---------------------------------------------------------------------------
__global__ __launch_bounds__(256) void count_edges(
    const int* __restrict__ ei, int* __restrict__ cnt)
{
    int e = blockIdx.x * 256 + threadIdx.x;
    if (e < EE) atomicAdd(&cnt[ei[EE + e]], 1);
}

__global__ __launch_bounds__(256) void build_offsets(
    const int* __restrict__ cnt, int* __restrict__ off, int* __restrict__ cursor)
{
    __shared__ int csum[256];
    const int tid = threadIdx.x;
    const int chunk = (NN + 255) / 256;   // 40
    int s = 0;
    for (int i = 0; i < chunk; ++i) {
        int idx = tid * chunk + i;
        if (idx < NN) s += cnt[idx];
    }
    csum[tid] = s;
    __syncthreads();
    if (tid == 0) {
        int run = 0;
        for (int i = 0; i < 256; ++i) { int c = csum[i]; csum[i] = run; run += c; }
    }
    __syncthreads();
    int run = csum[tid];
    for (int i = 0; i < chunk; ++i) {
        int idx = tid * chunk + i;
        if (idx < NN) {
            off[idx] = run; cursor[idx] = run;
            run += cnt[idx];
        }
    }
}

__global__ __launch_bounds__(256) void fill_csr(
    const int* __restrict__ ei, int* __restrict__ cursor, int* __restrict__ srclist)
{
    int e = blockIdx.x * 256 + threadIdx.x;
    if (e < EE) {
        int d = ei[EE + e];
        int pos = atomicAdd(&cursor[d], 1);
        srclist[pos] = ei[e];
    }
}

// ---------------------------------------------------------------------------
// K2b: agg[node] = sum over incoming edges of m[src]
// ---------------------------------------------------------------------------
__global__ __launch_bounds__(256) void gather_agg(
    const float* __restrict__ m, const int* __restrict__ off,
    const int* __restrict__ cnt, const int* __restrict__ srclist,
    float* __restrict__ agg)
{
    __shared__ int sl[128];
    const int node = blockIdx.x, tid = threadIdx.x;
    const int o0 = off[node], deg = cnt[node];
    float acc0 = 0.f, acc1 = 0.f;
    const int d0 = tid, d1 = tid + 256;
    for (int j0 = 0; j0 < deg; j0 += 128) {
        if (tid < 128 && j0 + tid < deg) sl[tid] = srclist[o0 + j0 + tid];
        __syncthreads();
        const int jn = (deg - j0 < 128) ? (deg - j0) : 128;
        for (int j = 0; j < jn; ++j) {
            const float* mr = &m[(size_t)sl[j] * DD];
            acc0 += mr[d0];
            if (d1 < DD) acc1 += mr[d1];
        }
        __syncthreads();
    }
    agg[(size_t)node * DD + d0] = acc0;
    if (d1 < DD) agg[(size_t)node * DD + d1] = acc1;
}

// ---------------------------------------------------------------------------
// K2c: fused GRU cell; 8 rows per block.
// ---------------------------------------------------------------------------
__global__ __launch_bounds__(256) void gru_step(
    const float* __restrict__ agg, const float* __restrict__ hin,
    const float* __restrict__ wih, const float* __restrict__ whh,
    const float* __restrict__ bih, const float* __restrict__ bhh,
    float* __restrict__ hout)
{
    __shared__ float al[8][DD], hl[8][DD];
    const int r0 = blockIdx.x * 8, tid = threadIdx.x;
    for (int i = tid; i < 8*DD; i += 256) {
        int r = i/DD, k = i%DD;
        al[r][k] = agg[(size_t)(r0+r)*DD + k];
        hl[r][k] = hin[(size_t)(r0+r)*DD + k];
    }
    __syncthreads();
    for (int d = tid; d < DD; d += 256) {
        float air[8]={0,0,0,0,0,0,0,0}, aiz[8]={0,0,0,0,0,0,0,0}, ain[8]={0,0,0,0,0,0,0,0};
        float ahr[8]={0,0,0,0,0,0,0,0}, ahz[8]={0,0,0,0,0,0,0,0}, ahn[8]={0,0,0,0,0,0,0,0};
        for (int k = 0; k < DD; ++k) {
            const float* wi = &wih[(size_t)k*1200 + d];
            float wir = wi[0], wiz = wi[400], win = wi[800];
            const float* wh = &whh[(size_t)k*1200 + d];
            float whr = wh[0], whz = wh[400], whn = wh[800];
            #pragma unroll
            for (int r = 0; r < 8; ++r) {
                float a = al[r][k], hh = hl[r][k];
                air[r] += a*wir; aiz[r] += a*wiz; ain[r] += a*win;
                ahr[r] += hh*whr; ahz[r] += hh*whz; ahn[r] += hh*whn;
            }
        }
        float bir = bih[d], biz = bih[d+400], bin = bih[d+800];
        float bhr = bhh[d], bhz = bhh[d+400], bhn = bhh[d+800];
        #pragma unroll
        for (int r = 0; r < 8; ++r) {
            float rg = 1.f/(1.f + __expf(-(air[r]+bir + ahr[r]+bhr)));
            float zg = 1.f/(1.f + __expf(-(aiz[r]+biz + ahz[r]+bhz)));
            float ng = tanhf(ain[r]+bin + rg*(ahn[r]+bhn));
            hout[(size_t)(r0+r)*DD + d] = (1.f-zg)*ng + zg*hl[r][d];
        }
    }
}

// ---------------------------------------------------------------------------
// K3a: clicked_total = concat(x_enc[midx], h[midx])*mask @ w_click + b_click
// ---------------------------------------------------------------------------
__global__ __launch_bounds__(256) void clicked_mm(
    const int* __restrict__ map, const float* __restrict__ xe,
    const float* __restrict__ hg, const float* __restrict__ wc,
    const float* __restrict__ bc, float* __restrict__ ct)
{
    __shared__ float a[8][2*DD];
    const int r0 = blockIdx.x * 8, tid = threadIdx.x;
    for (int i = tid; i < 8*2*DD; i += 256) {
        int r = i/(2*DD), k = i%(2*DD);
        int mi = map[r0 + r];
        float v = 0.f;
        if (mi >= 0) v = (k < DD) ? xe[(size_t)mi*DD + k] : hg[(size_t)mi*DD + (k-DD)];
        a[r][k] = v;
    }
    __syncthreads();
    for (int d = tid; d < DD; d += 256) {
        float acc[8] = {0,0,0,0,0,0,0,0};
        for (int k = 0; k < 2*DD; ++k) {
            float w = wc[(size_t)k*DD + d];
            #pragma unroll
            for (int r = 0; r < 8; ++r) acc[r] += a[r][k]*w;
        }
        float bb = bc[d];
        #pragma unroll
        for (int r = 0; r < 8; ++r) ct[(size_t)(r0+r)*DD + d] = acc[r] + bb;
    }
}

// ---------------------------------------------------------------------------
// K3b: uq/uk/uv = ct @ u_wq/u_wk/u_wv
// ---------------------------------------------------------------------------
__global__ __launch_bounds__(256) void user_qkv(
    const float* __restrict__ ct,
    const float* __restrict__ wq, const float* __restrict__ wk, const float* __restrict__ wv,
    float* __restrict__ uq, float* __restrict__ uk, float* __restrict__ uv)
{
    __shared__ float a[8][DD];
    const int r0 = blockIdx.x * 8, tid = threadIdx.x;
    for (int i = tid; i < 8*DD; i += 256)
        a[i/DD][i%DD] = ct[(size_t)(r0 + i/DD)*DD + i%DD];
    __syncthreads();
    for (int d = tid; d < DD; d += 256) {
        float aq[8]={0,0,0,0,0,0,0,0}, ak[8]={0,0,0,0,0,0,0,0}, av[8]={0,0,0,0,0,0,0,0};
        for (int k = 0; k < DD; ++k) {
            float wq_ = wq[(size_t)k*DD + d];
            float wk_ = wk[(size_t)k*DD + d];
            float wv_ = wv[(size_t)k*DD + d];
            #pragma unroll
            for (int r = 0; r < 8; ++r) {
                float x = a[r][k];
                aq[r] += x*wq_; ak[r] += x*wk_; av[r] += x*wv_;
            }
        }
        #pragma unroll
        for (int r = 0; r < 8; ++r) {
            uq[(size_t)(r0+r)*DD + d] = aq[r];
            uk[(size_t)(r0+r)*DD + d] = ak[r];
            uv[(size_t)(r0+r)*DD + d] = av[r];
        }
    }
}

// ---------------------------------------------------------------------------
// K3c: masked MHSA per (batch, head); block = 64 threads
// ---------------------------------------------------------------------------
__global__ __launch_bounds__(64) void user_attn(
    const float* __restrict__ uq, const float* __restrict__ uk,
    const float* __restrict__ uv, const int* __restrict__ map,
    float* __restrict__ uo)
{
    const int b = blockIdx.x / HH, h = blockIdx.x % HH, tid = threadIdx.x;
    __shared__ float q[NCK][DHD], k[NCK][DHD], v[NCK][DHD];
    __shared__ float sc[NCK][NCK+2];
    __shared__ float biasl[NCK];
    for (int i = tid; i < NCK*DHD; i += 64) {
        int c = i/DHD, d = i%DHD;
        size_t base = ((size_t)b*NCK + c)*DD + h*DHD + d;
        q[c][d] = uq[base]; k[c][d] = uk[base]; v[c][d] = uv[base];
    }
    for (int i = tid; i < NCK; i += 64)
        biasl[i] = (map[b*NCK + i] >= 0) ? 0.f : -1e9f;
    __syncthreads();
    for (int i = tid; i < NCK*NCK; i += 64) {
        int t = i/NCK, k2 = i%NCK;
        float s = 0.f;
        #pragma unroll
        for (int d4 = 0; d4 < 5; ++d4) {
            const float4 qa = *(const float4*)&q[t][d4*4];
            const float4 kb = *(const float4*)&k[k2][d4*4];
            s += qa.x*kb.x + qa.y*kb.y + qa.z*kb.z + qa.w*kb.w;
        }
        sc[t][k2] = s * 0.2236067977f + biasl[k2];
    }
    __syncthreads();
    if (tid < NCK) {
        float mx = -1e30f;
        for (int k2 = 0; k2 < NCK; ++k2) mx = fmaxf(mx, sc[tid][k2]);
        float ssum = 0.f;
        for (int k2 = 0; k2 < NCK; ++k2) { float e = __expf(sc[tid][k2]-mx); sc[tid][k2] = e; ssum += e; }
        float inv = 1.f/ssum;
        for (int k2 = 0; k2 < NCK; ++k2) sc[tid][k2] *= inv;
    }
    __syncthreads();
    for (int i = tid; i < NCK*DHD; i += 64) {
        int t = i/DHD, d = i%DHD;
        float o = 0.f;
        for (int k2 = 0; k2 < NCK; ++k2) o += sc[t][k2]*v[k2][d];
        uo[((size_t)b*NCK + t)*DD + h*DHD + d] = o;
    }
}

// ---------------------------------------------------------------------------
// K3d: masked attention pooling -> user_emb[b][400]; block per batch
// ---------------------------------------------------------------------------
__global__ __launch_bounds__(256) void user_pool(
    const float* __restrict__ uo, const int* __restrict__ map,
    const float* __restrict__ uwp, const float* __restrict__ uqp,
    float* __restrict__ user_emb)
{
    const int b = blockIdx.x, tid = threadIdx.x;
    __shared__ float alpha[64];
    __shared__ float red[256];
    for (int t = 0; t < NCK; ++t) {
        float partial = 0.f;
        const float* ur = uo + ((size_t)b*NCK + t)*DD;
        for (int p = tid; p < PP; p += 256) {
            float s = 0.f;
            for (int d = 0; d < DD; ++d) s += ur[d] * uwp[(size_t)d*PP + p];
            partial += tanhf(s) * uqp[p];
        }
        red[tid] = partial; __syncthreads();
        for (int st = 128; st > 0; st >>= 1) {
            if (tid < st) red[tid] += red[tid+st];
            __syncthreads();
        }
        if (tid == 0)
            alpha[t] = red[0] + ((map[b*NCK + t] >= 0) ? 0.f : -1e9f);
        __syncthreads();
    }
    if (tid == 0) {
        float mx = -1e30f;
        for (int t = 0; t < NCK; ++t) mx = fmaxf(mx, alpha[t]);
        float ssum = 0.f;
        for (int t = 0; t < NCK; ++t) { float e = __expf(alpha[t]-mx); alpha[t] = e; ssum += e; }
        float inv = 1.f/ssum;
        for (int t = 0; t < NCK; ++t) alpha[t] *= inv;
    }
    __syncthreads();
    for (int d = tid; d < DD; d += 256) {
        float acc = 0.f;
        for (int t = 0; t < NCK; ++t) acc += alpha[t] * uo[((size_t)b*NCK + t)*DD + d];
        user_emb[(size_t)b*DD + d] = acc;
    }
}

// ---------------------------------------------------------------------------
// K5: candidate scoring + NCE loss; single block
// ---------------------------------------------------------------------------
__global__ __launch_bounds__(256) void score_loss(
    const float* __restrict__ cr, const float* __restrict__ cf,
    const float* __restrict__ ue, const int* __restrict__ label,
    float* __restrict__ dout)
{
    __shared__ float sr[BB][NCAND], sf[BB][NCAND], red[BB];
    const int tid = threadIdx.x;
    for (int i = tid; i < 2*BB*NCAND; i += 256) {
        int which = i / (BB*NCAND);
        int r = i % (BB*NCAND);
        int b = r / NCAND, c = r % NCAND;
        const float* ce = (which ? cf : cr) + (size_t)r*DD;
        const float* u = ue + (size_t)b*DD;
        float s = 0.f;
        for (int d = 0; d < DD; ++d) s += ce[d]*u[d];
        if (which) sf[b][c] = s; else sr[b][c] = s;
        dout[1 + i] = s;
    }
    __syncthreads();
    if (tid < BB) {
        int b = tid;
        float mr = -1e30f, mf = -1e30f;
        for (int c = 0; c < NCAND; ++c) { mr = fmaxf(mr, sr[b][c]); mf = fmaxf(mf, sf[b][c]); }
        float er = 0.f, ef = 0.f;
        for (int c = 0; c < NCAND; ++c) { er += expf(sr[b][c]-mr); ef += expf(sf[b][c]-mf); }
        float lser = logf(er)+mr, lsef = logf(ef)+mf;
        int lab = label[b]; lab = lab < 0 ? 0 : (lab > NCAND-1 ? NCAND-1 : lab);
        float crb = lser - sr[b][lab];
        float cfb = 0.f;
        for (int c = 0; c < NCAND; ++c) cfb += (lsef - sf[b][c]);
        red[tid] = crb + 0.5f * (cfb / (float)NCAND);
    }
    __syncthreads();
    if (tid == 0) {
        float L = 0.f;
        for (int b = 0; b < BB; ++b) L += red[b];
        dout[0] = L / (float)BB;
    }
}

// ---------------------------------------------------------------------------
extern "C" void kernel_launch(void* const* d_in, const int* in_sizes, int n_in,
                              void* d_out, int out_size, void* d_ws, size_t ws_size,
                              hipStream_t stream) {
    (void)in_sizes; (void)n_in; (void)out_size; (void)ws_size;
    const int*   sub_x  = (const int*)d_in[0];
    const int*   edge   = (const int*)d_in[1];
    const int*   mapi   = (const int*)d_in[2];
    const int*   cand   = (const int*)d_in[3];
    const int*   fcand  = (const int*)d_in[4];
    const int*   label  = (const int*)d_in[5];
    const float* glove  = (const float*)d_in[6];
    const float* nwq    = (const float*)d_in[7];
    const float* nwk    = (const float*)d_in[8];
    const float* nwv    = (const float*)d_in[9];
    const float* nwp    = (const float*)d_in[10];
    const float* nqp    = (const float*)d_in[11];
    const float* ggc    = (const float*)d_in[12];
    const float* wih    = (const float*)d_in[13];
    const float* whh    = (const float*)d_in[14];
    const float* bih    = (const float*)d_in[15];
    const float* bhh    = (const float*)d_in[16];
    const float* wclick = (const float*)d_in[17];
    const float* bclick = (const float*)d_in[18];
    const float* uwq    = (const float*)d_in[19];
    const float* uwk    = (const float*)d_in[20];
    const float* uwv    = (const float*)d_in[21];
    const float* uwp    = (const float*)d_in[22];
    const float* uqp    = (const float*)d_in[23];

    // workspace layout (floats); ws_size = 256 MB
    float* ws     = (float*)d_ws;
    float* x_enc  = ws;                       // 4,000,000 f
    float* hbuf   = ws + 4000000;             // 4,000,000 f
    float* region = ws + 8000000;             // 8,000,000 f shared region
    float* mbuf   = region;                   // GGC: m
    float* aggbuf = region + 4000000;         // GGC: agg
    // after GGC, region reused:
    float* ct   = region;                     // 1,280,000
    float* uq   = region + 1280000;
    float* uk   = region + 2560000;
    float* uv   = region + 3840000;
    float* uo   = region + 5120000;           // 1,280,000
    float* user = region + 6400000;           // 25,600
    float* crnc = region + 6425600;           // 128,000
    float* cfnc = region + 6553600;           // 128,000
    // int area at byte offset 64 MB
    int* ibase   = (int*)((char*)d_ws + (size_t)64*1024*1024);
    int* cnt     = ibase;                     // 10,000
    int* off     = ibase + 10000;             // 10,000
    int* cursor  = ibase + 20000;             // 10,000
    int* srclist = ibase + 30000;             // 200,000
    // bf16 prepped weights, beyond int area
    unsigned short* Wt  = (unsigned short*)(ws + 17100000);  // 1200*320 shorts
    unsigned short* wpT = (unsigned short*)(ws + 17300000);  // 208*416 shorts

    // 0) prep transposed bf16 weights (tiny; L2-resident afterwards)
    prep_wt<<<1500, 256, 0, stream>>>(nwq, nwk, nwv, Wt);
    prep_wpt<<<338, 256, 0, stream>>>(nwp, wpT);

    // 1) encode all nodes
    news_enc<<<NN, 256, 0, stream>>>(sub_x, TOKS, glove, Wt, wpT, nqp, x_enc);

    // 1b) build CSR-by-destination once (reused by all 3 GGC layers)
    hipMemsetAsync(cnt, 0, NN*sizeof(int), stream);
    count_edges<<<(EE+255)/256, 256, 0, stream>>>(edge, cnt);
    build_offsets<<<1, 256, 0, stream>>>(cnt, off, cursor);
    fill_csr<<<(EE+255)/256, 256, 0, stream>>>(edge, cursor, srclist);

    // 2) GatedGraphConv x3 (gather instead of atomic scatter)
    const float* hin = x_enc;
    for (int l = 0; l < 3; ++l) {
        mm_nodes<<<NN/8, 256, 0, stream>>>(hin, ggc + (size_t)l*DD*DD, mbuf);
        gather_agg<<<NN, 256, 0, stream>>>(mbuf, off, cnt, srclist, aggbuf);
        gru_step<<<NN/8, 256, 0, stream>>>(aggbuf, hin, wih, whh, bih, bhh, hbuf);
        hin = hbuf;
    }

    // 3) click + user encoder
    clicked_mm<<<(BB*NCK)/8, 256, 0, stream>>>(mapi, x_enc, hbuf, wclick, bclick, ct);
    user_qkv<<<(BB*NCK)/8, 256, 0, stream>>>(ct, uwq, uwk, uwv, uq, uk, uv);
    user_attn<<<BB*HH, 64, 0, stream>>>(uq, uk, uv, mapi, uo);
    user_pool<<<BB, 256, 0, stream>>>(uo, mapi, uwp, uqp, user);

    // 4) candidates
    news_enc<<<BB*NCAND, 256, 0, stream>>>(cand,  TOKS, glove, Wt, wpT, nqp, crnc);
    news_enc<<<BB*NCAND, 256, 0, stream>>>(fcand, TOKS, glove, Wt, wpT, nqp, cfnc);

    // 5) scores + loss
    score_loss<<<1, 256, 0, stream>>>(crnc, cfnc, user, label, (float*)d_out);
}

// Round 7
// 3847.181 us; speedup vs baseline: 95.4787x; 1.2061x over previous
//
#include <hip/hip_runtime.h>
#include <cmath>

#define NN 10000
#define EE 200000
#define BB 64
#define NCK 50
#define NCAND 5
#define TOKS 38
#define TITLE 30
#define GDIM 300
#define HH 20
#define DHD 20
#define DD 400
#define PP 200

typedef __attribute__((ext_vector_type(8))) short bh8;
typedef __attribute__((ext_vector_type(4))) float f32x4;

__device__ __forceinline__ float bf2f(unsigned short u) {
    return __uint_as_float(((unsigned int)u) << 16);
}
__device__ __forceinline__ unsigned short f2bf(float f) {
    unsigned int u = __float_as_uint(f);
    u += 0x7fffu + ((u >> 16) & 1u);
    return (unsigned short)(u >> 16);
}

// ---------------------------------------------------------------------------
// prep: Wt[1200][320] bf16 = concat(wq,wk,wv) transposed, k-padded with zeros
// ---------------------------------------------------------------------------
__global__ __launch_bounds__(256) void prep_wt(
    const float* __restrict__ wq, const float* __restrict__ wk,
    const float* __restrict__ wv, unsigned short* __restrict__ Wt)
{
    int i = blockIdx.x * 256 + threadIdx.x;
    if (i >= 1200 * 320) return;
    int n = i / 320, k = i % 320;
    int m = n / 400, nn = n % 400;
    const float* W = (m == 0) ? wq : ((m == 1) ? wk : wv);
    float v = (k < GDIM) ? W[(size_t)k * DD + nn] : 0.f;
    Wt[i] = f2bf(v);
}

// prep: wpT[208][416] bf16 = wp[400][200] transposed, padded with zeros
__global__ __launch_bounds__(256) void prep_wpt(
    const float* __restrict__ wp, unsigned short* __restrict__ wpT)
{
    int i = blockIdx.x * 256 + threadIdx.x;
    if (i >= 208 * 416) return;
    int n = i / 416, k = i % 416;
    float v = (n < PP && k < DD) ? wp[(size_t)k * PP + n] : 0.f;
    wpT[i] = f2bf(v);
}

// prep: wggT[3][400][424] bf16 = ggc_w[l] transposed, k-padded
__global__ __launch_bounds__(256) void prep_wgg(
    const float* __restrict__ ggc, unsigned short* __restrict__ wggT)
{
    int i = blockIdx.x * 256 + threadIdx.x;
    if (i >= 3 * 400 * 424) return;
    int l = i / (400*424), rem = i % (400*424);
    int n = rem / 424, k = rem % 424;
    float v = (k < DD) ? ggc[(size_t)l*DD*DD + (size_t)k*DD + n] : 0.f;
    wggT[i] = f2bf(v);
}

// prep: wihT/whhT [1200][424] bf16 transposed, k-padded
__global__ __launch_bounds__(256) void prep_gruw(
    const float* __restrict__ wih, const float* __restrict__ whh,
    unsigned short* __restrict__ wihT, unsigned short* __restrict__ whhT)
{
    int i = blockIdx.x * 256 + threadIdx.x;
    if (i >= 1200 * 424) return;
    int n = i / 424, k = i % 424;
    wihT[i] = f2bf((k < DD) ? wih[(size_t)k*1200 + n] : 0.f);
    whhT[i] = f2bf((k < DD) ? whh[(size_t)k*1200 + n] : 0.f);
}

// ---------------------------------------------------------------------------
// K1: fused news encoder — MFMA QKV + merged MFMA attention+PV + MFMA pooling.
// One block (256 thr = 4 waves) per item. LDS ~54KB -> 3 blocks/CU.
// P is written into the dead q-slice of qS (wave-exclusive); ordering by
// s_waitcnt lgkmcnt(0) + sched_barrier(0) (same-wave LDS RAW).
// ---------------------------------------------------------------------------
__global__ __launch_bounds__(256, 3) void news_enc(
    const int* __restrict__ tokens, int tok_stride,
    const float* __restrict__ glove,
    const unsigned short* __restrict__ Wt,     // [1200][320] bf16
    const unsigned short* __restrict__ wpT,    // [208][416] bf16
    const float* __restrict__ qp,
    float* __restrict__ out_enc)
{
    // union: embS [32][328] bf16 (20992B)  |  qS/kS/vT [4][32][32] bf16 (24576B)
    __shared__ __align__(16) unsigned char uS[24576];
    __shared__ __align__(16) unsigned short outS[32 * 424];    // 27136B
    __shared__ float poolP[32][16];
    __shared__ int   tokS[32];
    __shared__ float alphaS[32];

    unsigned short* embS = (unsigned short*)uS;      // [32][328]
    unsigned short* qS   = (unsigned short*)uS;      // [4][32][32]
    unsigned short* kS   = qS + 4*32*32;
    unsigned short* vT   = kS + 4*32*32;

    const int tid  = threadIdx.x;
    const int item = blockIdx.x;
    const int w    = tid >> 6;        // wave 0..3
    const int lane = tid & 63;
    const int g    = lane >> 4;       // k-group 0..3
    const int l15  = lane & 15;

    if (tid < TITLE) tokS[tid] = tokens[(size_t)item * tok_stride + tid];
    for (int i = tid; i < (32*328)/2; i += 256) ((unsigned int*)embS)[i] = 0u;
    for (int i = tid; i < (32*424)/2; i += 256) ((unsigned int*)outS)[i] = 0u;
    __syncthreads();

    // gather glove rows -> embS bf16
    for (int i = tid; i < TITLE * 75; i += 256) {
        int t = i / 75, g4 = i % 75;
        const float4 v = *(const float4*)&glove[(size_t)tokS[t] * GDIM + g4 * 4];
        embS[t*328 + g4*4+0] = f2bf(v.x);
        embS[t*328 + g4*4+1] = f2bf(v.y);
        embS[t*328 + g4*4+2] = f2bf(v.z);
        embS[t*328 + g4*4+3] = f2bf(v.w);
    }
    __syncthreads();

    // preload A-fragments (emb rows): 2 m-tiles x 10 k-steps (80 VGPR)
    bh8 afr[2][10];
    #pragma unroll
    for (int mt = 0; mt < 2; ++mt)
        #pragma unroll
        for (int ks = 0; ks < 10; ++ks)
            afr[mt][ks] = *(const bh8*)&embS[(mt*16 + l15)*328 + ks*32 + g*8];
    __syncthreads();   // all waves done with embS -> union reusable

    // zero k-pads of qS/kS (k 20..31) and vT rows d=20..31
    for (int i = tid; i < 4*32*12; i += 256) {
        int h2 = i / (32*12), rem = i % (32*12);
        int row = rem / 12, kk = 20 + rem % 12;
        qS[(h2*32 + row)*32 + kk] = 0;
        kS[(h2*32 + row)*32 + kk] = 0;
        vT[(h2*32 + kk)*32 + row] = 0;
    }
    __syncthreads();

    const float sc = 0.2236067977f;

    for (int hg = 0; hg < 5; ++hg) {
        // ---- QKV via MFMA: 15 n-tiles (q|k|v x 5) over 4 waves ----
        for (int tt = 0; tt < 4; ++tt) {
            int t = w * 4 + tt;
            if (t < 15) {
                int m = t / 5, loc = t % 5;
                const unsigned short* wb =
                    Wt + (size_t)(m*400 + hg*80 + loc*16 + l15) * 320;
                f32x4 c0 = {0.f,0.f,0.f,0.f}, c1 = {0.f,0.f,0.f,0.f};
                #pragma unroll
                for (int ks = 0; ks < 10; ++ks) {
                    bh8 b = *(const bh8*)&wb[ks*32 + g*8];
                    c0 = __builtin_amdgcn_mfma_f32_16x16x32_bf16(afr[0][ks], b, c0, 0, 0, 0);
                    c1 = __builtin_amdgcn_mfma_f32_16x16x32_bf16(afr[1][ks], b, c1, 0, 0, 0);
                }
                int c2 = loc*16 + l15, h2 = c2 / 20, dloc = c2 % 20;
                #pragma unroll
                for (int r = 0; r < 4; ++r) {
                    int row0 = g*4 + r, row1 = 16 + g*4 + r;
                    if (m == 0) {
                        qS[(h2*32 + row0)*32 + dloc] = f2bf(c0[r]);
                        qS[(h2*32 + row1)*32 + dloc] = f2bf(c1[r]);
                    } else if (m == 1) {
                        kS[(h2*32 + row0)*32 + dloc] = f2bf(c0[r]);
                        kS[(h2*32 + row1)*32 + dloc] = f2bf(c1[r]);
                    } else {
                        vT[(h2*32 + dloc)*32 + row0] = f2bf(c0[r]);
                        vT[(h2*32 + dloc)*32 + row1] = f2bf(c1[r]);
                    }
                }
            }
        }
        __syncthreads();

        // ---- attention + PV merged, one wave per head (wave-exclusive data) ----
        {
            const int h = w;
            unsigned short* qh = qS + h*32*32;
            const unsigned short* kh = kS + h*32*32;
            const unsigned short* vh = vT + h*32*32;
            bh8 a0 = *(const bh8*)&qh[l15*32 + g*8];
            bh8 a1 = *(const bh8*)&qh[(16+l15)*32 + g*8];
            bh8 b0 = *(const bh8*)&kh[l15*32 + g*8];
            bh8 b1 = *(const bh8*)&kh[(16+l15)*32 + g*8];
            bh8 vb0 = *(const bh8*)&vh[l15*32 + g*8];
            bh8 vb1 = *(const bh8*)&vh[(16+l15)*32 + g*8];
            f32x4 s00 = {0.f,0.f,0.f,0.f}, s01 = {0.f,0.f,0.f,0.f};
            f32x4 s10 = {0.f,0.f,0.f,0.f}, s11 = {0.f,0.f,0.f,0.f};
            s00 = __builtin_amdgcn_mfma_f32_16x16x32_bf16(a0, b0, s00, 0, 0, 0);
            s01 = __builtin_amdgcn_mfma_f32_16x16x32_bf16(a0, b1, s01, 0, 0, 0);
            s10 = __builtin_amdgcn_mfma_f32_16x16x32_bf16(a1, b0, s10, 0, 0, 0);
            s11 = __builtin_amdgcn_mfma_f32_16x16x32_bf16(a1, b1, s11, 0, 0, 0);
            const float maskv = (l15 >= 14) ? -1e30f : 0.f;   // key cols >=30
            #pragma unroll
            for (int r = 0; r < 4; ++r) {
                {
                    float v0 = s00[r]*sc, v1 = s01[r]*sc + maskv;
                    float mx = fmaxf(v0, v1);
                    #pragma unroll
                    for (int mk = 1; mk < 16; mk <<= 1) mx = fmaxf(mx, __shfl_xor(mx, mk));
                    float e0 = __expf(v0 - mx), e1 = __expf(v1 - mx);
                    float ssum = e0 + e1;
                    #pragma unroll
                    for (int mk = 1; mk < 16; mk <<= 1) ssum += __shfl_xor(ssum, mk);
                    float inv = 1.f / ssum;
                    qh[(g*4+r)*32 + l15]      = f2bf(e0*inv);
                    qh[(g*4+r)*32 + 16 + l15] = f2bf(e1*inv);
                }
                {
                    float v0 = s10[r]*sc, v1 = s11[r]*sc + maskv;
                    float mx = fmaxf(v0, v1);
                    #pragma unroll
                    for (int mk = 1; mk < 16; mk <<= 1) mx = fmaxf(mx, __shfl_xor(mx, mk));
                    float e0 = __expf(v0 - mx), e1 = __expf(v1 - mx);
                    float ssum = e0 + e1;
                    #pragma unroll
                    for (int mk = 1; mk < 16; mk <<= 1) ssum += __shfl_xor(ssum, mk);
                    float inv = 1.f / ssum;
                    qh[(16+g*4+r)*32 + l15]      = f2bf(e0*inv);
                    qh[(16+g*4+r)*32 + 16 + l15] = f2bf(e1*inv);
                }
            }
            // same-wave LDS RAW fence: drain ds_writes, forbid hoisting reads
            asm volatile("s_waitcnt lgkmcnt(0)" ::: "memory");
            __builtin_amdgcn_sched_barrier(0);
            bh8 pa0 = *(const bh8*)&qh[l15*32 + g*8];
            bh8 pa1 = *(const bh8*)&qh[(16+l15)*32 + g*8];
            f32x4 o00 = {0.f,0.f,0.f,0.f}, o01 = {0.f,0.f,0.f,0.f};
            f32x4 o10 = {0.f,0.f,0.f,0.f}, o11 = {0.f,0.f,0.f,0.f};
            o00 = __builtin_amdgcn_mfma_f32_16x16x32_bf16(pa0, vb0, o00, 0, 0, 0);
            o01 = __builtin_amdgcn_mfma_f32_16x16x32_bf16(pa0, vb1, o01, 0, 0, 0);
            o10 = __builtin_amdgcn_mfma_f32_16x16x32_bf16(pa1, vb0, o10, 0, 0, 0);
            o11 = __builtin_amdgcn_mfma_f32_16x16x32_bf16(pa1, vb1, o11, 0, 0, 0);
            int base = hg*80 + w*20;
            #pragma unroll
            for (int r = 0; r < 4; ++r) {
                int row0 = g*4 + r, row1 = 16 + g*4 + r;
                outS[row0*424 + base + l15] = f2bf(o00[r]);
                if (l15 < 4) outS[row0*424 + base + 16 + l15] = f2bf(o01[r]);
                if (row1 < TITLE) {
                    outS[row1*424 + base + l15] = f2bf(o10[r]);
                    if (l15 < 4) outS[row1*424 + base + 16 + l15] = f2bf(o11[r]);
                }
            }
        }
        __syncthreads();
    }

    // ---- pooling scores via MFMA: tanh(out@wp) @ qp ----
    for (int i = tid; i < 32*16; i += 256) poolP[i/16][i%16] = 0.f;
    __syncthreads();
    for (int tt = 0; tt < 4; ++tt) {
        int t = w * 4 + tt;
        if (t < 13) {
            const unsigned short* wb = wpT + (size_t)(t*16 + l15) * 416;
            f32x4 c0 = {0.f,0.f,0.f,0.f}, c1 = {0.f,0.f,0.f,0.f};
            #pragma unroll
            for (int ks = 0; ks < 13; ++ks) {
                bh8 a0 = *(const bh8*)&outS[l15*424 + ks*32 + g*8];
                bh8 a1 = *(const bh8*)&outS[(16+l15)*424 + ks*32 + g*8];
                bh8 b  = *(const bh8*)&wb[ks*32 + g*8];
                c0 = __builtin_amdgcn_mfma_f32_16x16x32_bf16(a0, b, c0, 0, 0, 0);
                c1 = __builtin_amdgcn_mfma_f32_16x16x32_bf16(a1, b, c1, 0, 0, 0);
            }
            int n = t*16 + l15;
            float qpn = (n < PP) ? qp[n] : 0.f;
            #pragma unroll
            for (int r = 0; r < 4; ++r) {
                float v0 = tanhf(c0[r]) * qpn;
                float v1 = tanhf(c1[r]) * qpn;
                #pragma unroll
                for (int mk = 1; mk < 16; mk <<= 1) {
                    v0 += __shfl_xor(v0, mk);
                    v1 += __shfl_xor(v1, mk);
                }
                if (l15 == 0) {
                    poolP[g*4+r][t]    = v0;
                    poolP[16+g*4+r][t] = v1;
                }
            }
        }
    }
    __syncthreads();
    if (tid < TITLE) {
        float s = 0.f;
        for (int t = 0; t < 13; ++t) s += poolP[tid][t];
        alphaS[tid] = s;
    }
    __syncthreads();
    if (tid == 0) {
        float mx = -1e30f;
        for (int t = 0; t < TITLE; ++t) mx = fmaxf(mx, alphaS[t]);
        float ss = 0.f;
        for (int t = 0; t < TITLE; ++t) { float e = __expf(alphaS[t]-mx); alphaS[t] = e; ss += e; }
        float inv = 1.f / ss;
        for (int t = 0; t < TITLE; ++t) alphaS[t] *= inv;
    }
    __syncthreads();
    for (int dd = tid; dd < DD; dd += 256) {
        float a = 0.f;
        for (int t = 0; t < TITLE; ++t) a += alphaS[t] * bf2f(outS[t*424 + dd]);
        out_enc[(size_t)item*DD + dd] = a;
    }
}

// ---------------------------------------------------------------------------
// K2a: m = h @ W via MFMA; 32 rows/block, writes m as bf16
// ---------------------------------------------------------------------------
__global__ __launch_bounds__(256, 3) void mm_nodes_mfma(
    const float* __restrict__ A, const unsigned short* __restrict__ WT,
    unsigned short* __restrict__ Mo)
{
    __shared__ __align__(16) unsigned short aS[32 * 424];
    const int r0 = blockIdx.x * 32, tid = threadIdx.x;
    const int w = tid >> 6, lane = tid & 63, g = lane >> 4, l15 = lane & 15;
    for (int i = tid; i < 32*424; i += 256) {
        int r = i / 424, c = i % 424;
        int grow = r0 + r;
        float v = (grow < NN && c < DD) ? A[(size_t)grow*DD + c] : 0.f;
        aS[i] = f2bf(v);
    }
    __syncthreads();
    for (int t = w; t < 25; t += 4) {
        const unsigned short* wb = WT + (size_t)(t*16 + l15) * 424;
        f32x4 c0 = {0.f,0.f,0.f,0.f}, c1 = {0.f,0.f,0.f,0.f};
        #pragma unroll
        for (int ks = 0; ks < 13; ++ks) {
            bh8 a0 = *(const bh8*)&aS[l15*424 + ks*32 + g*8];
            bh8 a1 = *(const bh8*)&aS[(16+l15)*424 + ks*32 + g*8];
            bh8 b  = *(const bh8*)&wb[ks*32 + g*8];
            c0 = __builtin_amdgcn_mfma_f32_16x16x32_bf16(a0, b, c0, 0, 0, 0);
            c1 = __builtin_amdgcn_mfma_f32_16x16x32_bf16(a1, b, c1, 0, 0, 0);
        }
        int d = t*16 + l15;
        #pragma unroll
        for (int r = 0; r < 4; ++r) {
            int row = r0 + g*4 + r;
            if (row < NN) Mo[(size_t)row*DD + d] = f2bf(c0[r]);
            row += 16;
            if (row < NN) Mo[(size_t)row*DD + d] = f2bf(c1[r]);
        }
    }
}

// ---------------------------------------------------------------------------
// CSR build: count -> exclusive scan -> cursor scatter
// ---------------------------------------------------------------------------
__global__ __launch_bounds__(256) void count_edges(
    const int* __restrict__ ei, int* __restrict__ cnt)
{
    int e = blockIdx.x * 256 + threadIdx.x;
    if (e < EE) atomicAdd(&cnt[ei[EE + e]], 1);
}

__global__ __launch_bounds__(256) void build_offsets(
    const int* __restrict__ cnt, int* __restrict__ off, int* __restrict__ cursor)
{
    __shared__ int csum[256];
    const int tid = threadIdx.x;
    const int chunk = (NN + 255) / 256;   // 40
    int s = 0;
    for (int i = 0; i < chunk; ++i) {
        int idx = tid * chunk + i;
        if (idx < NN) s += cnt[idx];
    }
    csum[tid] = s;
    __syncthreads();
    if (tid == 0) {
        int run = 0;
        for (int i = 0; i < 256; ++i) { int c = csum[i]; csum[i] = run; run += c; }
    }
    __syncthreads();
    int run = csum[tid];
    for (int i = 0; i < chunk; ++i) {
        int idx = tid * chunk + i;
        if (idx < NN) {
            off[idx] = run; cursor[idx] = run;
            run += cnt[idx];
        }
    }
}

__global__ __launch_bounds__(256) void fill_csr(
    const int* __restrict__ ei, int* __restrict__ cursor, int* __restrict__ srclist)
{
    int e = blockIdx.x * 256 + threadIdx.x;
    if (e < EE) {
        int d = ei[EE + e];
        int pos = atomicAdd(&cursor[d], 1);
        srclist[pos] = ei[e];
    }
}

// ---------------------------------------------------------------------------
// K2b: agg[node] = sum over incoming edges of m[src]  (m is bf16)
// ---------------------------------------------------------------------------
__global__ __launch_bounds__(256) void gather_agg(
    const unsigned short* __restrict__ m, const int* __restrict__ off,
    const int* __restrict__ cnt, const int* __restrict__ srclist,
    float* __restrict__ agg)
{
    __shared__ int sl[128];
    const int node = blockIdx.x, tid = threadIdx.x;
    const int o0 = off[node], deg = cnt[node];
    float acc0 = 0.f, acc1 = 0.f;
    const int d0 = tid, d1 = tid + 256;
    for (int j0 = 0; j0 < deg; j0 += 128) {
        if (tid < 128 && j0 + tid < deg) sl[tid] = srclist[o0 + j0 + tid];
        __syncthreads();
        const int jn = (deg - j0 < 128) ? (deg - j0) : 128;
        for (int j = 0; j < jn; ++j) {
            const unsigned short* mr = &m[(size_t)sl[j] * DD];
            acc0 += bf2f(mr[d0]);
            if (d1 < DD) acc1 += bf2f(mr[d1]);
        }
        __syncthreads();
    }
    agg[(size_t)node * DD + d0] = acc0;
    if (d1 < DD) agg[(size_t)node * DD + d1] = acc1;
}

// ---------------------------------------------------------------------------
// K2c: GRU cell via MFMA; 32 rows/block. Gates in f32; z*h uses exact f32 h.
// Safe in-place (hin may == hout): each element read+written by same thread.
// ---------------------------------------------------------------------------
__global__ __launch_bounds__(256, 3) void gru_step_mfma(
    const float* __restrict__ agg, const float* __restrict__ hin,
    const unsigned short* __restrict__ wihT, const unsigned short* __restrict__ whhT,
    const float* __restrict__ bih, const float* __restrict__ bhh,
    float* __restrict__ hout)
{
    __shared__ __align__(16) unsigned short aggS[32 * 424];
    __shared__ __align__(16) unsigned short hS[32 * 424];
    const int r0 = blockIdx.x * 32, tid = threadIdx.x;
    const int w = tid >> 6, lane = tid & 63, g = lane >> 4, l15 = lane & 15;
    for (int i = tid; i < 32*424; i += 256) {
        int r = i / 424, c = i % 424;
        int grow = r0 + r;
        float va = 0.f, vh = 0.f;
        if (grow < NN && c < DD) {
            va = agg[(size_t)grow*DD + c];
            vh = hin[(size_t)grow*DD + c];
        }
        aggS[i] = f2bf(va); hS[i] = f2bf(vh);
    }
    __syncthreads();
    for (int t = w; t < 25; t += 4) {
        int d = t*16 + l15;
        const unsigned short* bri = wihT + (size_t)d * 424;
        const unsigned short* bzi = wihT + (size_t)(400 + d) * 424;
        const unsigned short* bni = wihT + (size_t)(800 + d) * 424;
        const unsigned short* brh = whhT + (size_t)d * 424;
        const unsigned short* bzh = whhT + (size_t)(400 + d) * 424;
        const unsigned short* bnh = whhT + (size_t)(800 + d) * 424;
        f32x4 ir0={0.f,0.f,0.f,0.f}, ir1={0.f,0.f,0.f,0.f};
        f32x4 iz0={0.f,0.f,0.f,0.f}, iz1={0.f,0.f,0.f,0.f};
        f32x4 in0={0.f,0.f,0.f,0.f}, in1={0.f,0.f,0.f,0.f};
        f32x4 hr0={0.f,0.f,0.f,0.f}, hr1={0.f,0.f,0.f,0.f};
        f32x4 hz0={0.f,0.f,0.f,0.f}, hz1={0.f,0.f,0.f,0.f};
        f32x4 hn0={0.f,0.f,0.f,0.f}, hn1={0.f,0.f,0.f,0.f};
        #pragma unroll
        for (int ks = 0; ks < 13; ++ks) {
            bh8 aa0 = *(const bh8*)&aggS[l15*424 + ks*32 + g*8];
            bh8 aa1 = *(const bh8*)&aggS[(16+l15)*424 + ks*32 + g*8];
            bh8 ah0 = *(const bh8*)&hS[l15*424 + ks*32 + g*8];
            bh8 ah1 = *(const bh8*)&hS[(16+l15)*424 + ks*32 + g*8];
            bh8 b0 = *(const bh8*)&bri[ks*32 + g*8];
            bh8 b1 = *(const bh8*)&bzi[ks*32 + g*8];
            bh8 b2 = *(const bh8*)&bni[ks*32 + g*8];
            bh8 b3 = *(const bh8*)&brh[ks*32 + g*8];
            bh8 b4 = *(const bh8*)&bzh[ks*32 + g*8];
            bh8 b5 = *(const bh8*)&bnh[ks*32 + g*8];
            ir0 = __builtin_amdgcn_mfma_f32_16x16x32_bf16(aa0, b0, ir0, 0, 0, 0);
            ir1 = __builtin_amdgcn_mfma_f32_16x16x32_bf16(aa1, b0, ir1, 0, 0, 0);
            iz0 = __builtin_amdgcn_mfma_f32_16x16x32_bf16(aa0, b1, iz0, 0, 0, 0);
            iz1 = __builtin_amdgcn_mfma_f32_16x16x32_bf16(aa1, b1, iz1, 0, 0, 0);
            in0 = __builtin_amdgcn_mfma_f32_16x16x32_bf16(aa0, b2, in0, 0, 0, 0);
            in1 = __builtin_amdgcn_mfma_f32_16x16x32_bf16(aa1, b2, in1, 0, 0, 0);
            hr0 = __builtin_amdgcn_mfma_f32_16x16x32_bf16(ah0, b3, hr0, 0, 0, 0);
            hr1 = __builtin_amdgcn_mfma_f32_16x16x32_bf16(ah1, b3, hr1, 0, 0, 0);
            hz0 = __builtin_amdgcn_mfma_f32_16x16x32_bf16(ah0, b4, hz0, 0, 0, 0);
            hz1 = __builtin_amdgcn_mfma_f32_16x16x32_bf16(ah1, b4, hz1, 0, 0, 0);
            hn0 = __builtin_amdgcn_mfma_f32_16x16x32_bf16(ah0, b5, hn0, 0, 0, 0);
            hn1 = __builtin_amdgcn_mfma_f32_16x16x32_bf16(ah1, b5, hn1, 0, 0, 0);
        }
        float bir = bih[d], biz = bih[400+d], bin = bih[800+d];
        float bhr = bhh[d], bhz = bhh[400+d], bhn = bhh[800+d];
        #pragma unroll
        for (int r = 0; r < 4; ++r) {
            {
                int grow = r0 + g*4 + r;
                if (grow < NN) {
                    float hl = hin[(size_t)grow*DD + d];
                    float rg = 1.f/(1.f + __expf(-(ir0[r]+bir + hr0[r]+bhr)));
                    float zg = 1.f/(1.f + __expf(-(iz0[r]+biz + hz0[r]+bhz)));
                    float ng = tanhf(in0[r]+bin + rg*(hn0[r]+bhn));
                    hout[(size_t)grow*DD + d] = (1.f-zg)*ng + zg*hl;
                }
            }
            {
                int grow = r0 + 16 + g*4 + r;
                if (grow < NN) {
                    float hl = hin[(size_t)grow*DD + d];
                    float rg = 1.f/(1.f + __expf(-(ir1[r]+bir + hr1[r]+bhr)));
                    float zg = 1.f/(1.f + __expf(-(iz1[r]+biz + hz1[r]+bhz)));
                    float ng = tanhf(in1[r]+bin + rg*(hn1[r]+bhn));
                    hout[(size_t)grow*DD + d] = (1.f-zg)*ng + zg*hl;
                }
            }
        }
    }
}

// ---------------------------------------------------------------------------
// K3a: clicked_total = concat(x_enc[midx], h[midx])*mask @ w_click + b_click
// ---------------------------------------------------------------------------
__global__ __launch_bounds__(256) void clicked_mm(
    const int* __restrict__ map, const float* __restrict__ xe,
    const float* __restrict__ hg, const float* __restrict__ wc,
    const float* __restrict__ bc, float* __restrict__ ct)
{
    __shared__ float a[8][2*DD];
    const int r0 = blockIdx.x * 8, tid = threadIdx.x;
    for (int i = tid; i < 8*2*DD; i += 256) {
        int r = i/(2*DD), k = i%(2*DD);
        int mi = map[r0 + r];
        float v = 0.f;
        if (mi >= 0) v = (k < DD) ? xe[(size_t)mi*DD + k] : hg[(size_t)mi*DD + (k-DD)];
        a[r][k] = v;
    }
    __syncthreads();
    for (int d = tid; d < DD; d += 256) {
        float acc[8] = {0,0,0,0,0,0,0,0};
        for (int k = 0; k < 2*DD; ++k) {
            float w = wc[(size_t)k*DD + d];
            #pragma unroll
            for (int r = 0; r < 8; ++r) acc[r] += a[r][k]*w;
        }
        float bb = bc[d];
        #pragma unroll
        for (int r = 0; r < 8; ++r) ct[(size_t)(r0+r)*DD + d] = acc[r] + bb;
    }
}

// ---------------------------------------------------------------------------
// K3b: uq/uk/uv = ct @ u_wq/u_wk/u_wv
// ---------------------------------------------------------------------------
__global__ __launch_bounds__(256) void user_qkv(
    const float* __restrict__ ct,
    const float* __restrict__ wq, const float* __restrict__ wk, const float* __restrict__ wv,
    float* __restrict__ uq, float* __restrict__ uk, float* __restrict__ uv)
{
    __shared__ float a[8][DD];
    const int r0 = blockIdx.x * 8, tid = threadIdx.x;
    for (int i = tid; i < 8*DD; i += 256)
        a[i/DD][i%DD] = ct[(size_t)(r0 + i/DD)*DD + i%DD];
    __syncthreads();
    for (int d = tid; d < DD; d += 256) {
        float aq[8]={0,0,0,0,0,0,0,0}, ak[8]={0,0,0,0,0,0,0,0}, av[8]={0,0,0,0,0,0,0,0};
        for (int k = 0; k < DD; ++k) {
            float wq_ = wq[(size_t)k*DD + d];
            float wk_ = wk[(size_t)k*DD + d];
            float wv_ = wv[(size_t)k*DD + d];
            #pragma unroll
            for (int r = 0; r < 8; ++r) {
                float x = a[r][k];
                aq[r] += x*wq_; ak[r] += x*wk_; av[r] += x*wv_;
            }
        }
        #pragma unroll
        for (int r = 0; r < 8; ++r) {
            uq[(size_t)(r0+r)*DD + d] = aq[r];
            uk[(size_t)(r0+r)*DD + d] = ak[r];
            uv[(size_t)(r0+r)*DD + d] = av[r];
        }
    }
}

// ---------------------------------------------------------------------------
// K3c: masked MHSA per (batch, head); block = 64 threads
// ---------------------------------------------------------------------------
__global__ __launch_bounds__(64) void user_attn(
    const float* __restrict__ uq, const float* __restrict__ uk,
    const float* __restrict__ uv, const int* __restrict__ map,
    float* __restrict__ uo)
{
    const int b = blockIdx.x / HH, h = blockIdx.x % HH, tid = threadIdx.x;
    __shared__ float q[NCK][DHD], k[NCK][DHD], v[NCK][DHD];
    __shared__ float sc[NCK][NCK+2];
    __shared__ float biasl[NCK];
    for (int i = tid; i < NCK*DHD; i += 64) {
        int c = i/DHD, d = i%DHD;
        size_t base = ((size_t)b*NCK + c)*DD + h*DHD + d;
        q[c][d] = uq[base]; k[c][d] = uk[base]; v[c][d] = uv[base];
    }
    for (int i = tid; i < NCK; i += 64)
        biasl[i] = (map[b*NCK + i] >= 0) ? 0.f : -1e9f;
    __syncthreads();
    for (int i = tid; i < NCK*NCK; i += 64) {
        int t = i/NCK, k2 = i%NCK;
        float s = 0.f;
        #pragma unroll
        for (int d4 = 0; d4 < 5; ++d4) {
            const float4 qa = *(const float4*)&q[t][d4*4];
            const float4 kb = *(const float4*)&k[k2][d4*4];
            s += qa.x*kb.x + qa.y*kb.y + qa.z*kb.z + qa.w*kb.w;
        }
        sc[t][k2] = s * 0.2236067977f + biasl[k2];
    }
    __syncthreads();
    if (tid < NCK) {
        float mx = -1e30f;
        for (int k2 = 0; k2 < NCK; ++k2) mx = fmaxf(mx, sc[tid][k2]);
        float ssum = 0.f;
        for (int k2 = 0; k2 < NCK; ++k2) { float e = __expf(sc[tid][k2]-mx); sc[tid][k2] = e; ssum += e; }
        float inv = 1.f/ssum;
        for (int k2 = 0; k2 < NCK; ++k2) sc[tid][k2] *= inv;
    }
    __syncthreads();
    for (int i = tid; i < NCK*DHD; i += 64) {
        int t = i/DHD, d = i%DHD;
        float o = 0.f;
        for (int k2 = 0; k2 < NCK; ++k2) o += sc[t][k2]*v[k2][d];
        uo[((size_t)b*NCK + t)*DD + h*DHD + d] = o;
    }
}

// ---------------------------------------------------------------------------
// K3d: masked attention pooling -> user_emb[b][400]; block per batch
// ---------------------------------------------------------------------------
__global__ __launch_bounds__(256) void user_pool(
    const float* __restrict__ uo, const int* __restrict__ map,
    const float* __restrict__ uwp, const float* __restrict__ uqp,
    float* __restrict__ user_emb)
{
    const int b = blockIdx.x, tid = threadIdx.x;
    __shared__ float alpha[64];
    __shared__ float red[256];
    for (int t = 0; t < NCK; ++t) {
        float partial = 0.f;
        const float* ur = uo + ((size_t)b*NCK + t)*DD;
        for (int p = tid; p < PP; p += 256) {
            float s = 0.f;
            for (int d = 0; d < DD; ++d) s += ur[d] * uwp[(size_t)d*PP + p];
            partial += tanhf(s) * uqp[p];
        }
        red[tid] = partial; __syncthreads();
        for (int st = 128; st > 0; st >>= 1) {
            if (tid < st) red[tid] += red[tid+st];
            __syncthreads();
        }
        if (tid == 0)
            alpha[t] = red[0] + ((map[b*NCK + t] >= 0) ? 0.f : -1e9f);
        __syncthreads();
    }
    if (tid == 0) {
        float mx = -1e30f;
        for (int t = 0; t < NCK; ++t) mx = fmaxf(mx, alpha[t]);
        float ssum = 0.f;
        for (int t = 0; t < NCK; ++t) { float e = __expf(alpha[t]-mx); alpha[t] = e; ssum += e; }
        float inv = 1.f/ssum;
        for (int t = 0; t < NCK; ++t) alpha[t] *= inv;
    }
    __syncthreads();
    for (int d = tid; d < DD; d += 256) {
        float acc = 0.f;
        for (int t = 0; t < NCK; ++t) acc += alpha[t] * uo[((size_t)b*NCK + t)*DD + d];
        user_emb[(size_t)b*DD + d] = acc;
    }
}

// ---------------------------------------------------------------------------
// K5: candidate scoring + NCE loss; single block
// ---------------------------------------------------------------------------
__global__ __launch_bounds__(256) void score_loss(
    const float* __restrict__ cr, const float* __restrict__ cf,
    const float* __restrict__ ue, const int* __restrict__ label,
    float* __restrict__ dout)
{
    __shared__ float sr[BB][NCAND], sf[BB][NCAND], red[BB];
    const int tid = threadIdx.x;
    for (int i = tid; i < 2*BB*NCAND; i += 256) {
        int which = i / (BB*NCAND);
        int r = i % (BB*NCAND);
        int b = r / NCAND, c = r % NCAND;
        const float* ce = (which ? cf : cr) + (size_t)r*DD;
        const float* u = ue + (size_t)b*DD;
        float s = 0.f;
        for (int d = 0; d < DD; ++d) s += ce[d]*u[d];
        if (which) sf[b][c] = s; else sr[b][c] = s;
        dout[1 + i] = s;
    }
    __syncthreads();
    if (tid < BB) {
        int b = tid;
        float mr = -1e30f, mf = -1e30f;
        for (int c = 0; c < NCAND; ++c) { mr = fmaxf(mr, sr[b][c]); mf = fmaxf(mf, sf[b][c]); }
        float er = 0.f, ef = 0.f;
        for (int c = 0; c < NCAND; ++c) { er += expf(sr[b][c]-mr); ef += expf(sf[b][c]-mf); }
        float lser = logf(er)+mr, lsef = logf(ef)+mf;
        int lab = label[b]; lab = lab < 0 ? 0 : (lab > NCAND-1 ? NCAND-1 : lab);
        float crb = lser - sr[b][lab];
        float cfb = 0.f;
        for (int c = 0; c < NCAND; ++c) cfb += (lsef - sf[b][c]);
        red[tid] = crb + 0.5f * (cfb / (float)NCAND);
    }
    __syncthreads();
    if (tid == 0) {
        float L = 0.f;
        for (int b = 0; b < BB; ++b) L += red[b];
        dout[0] = L / (float)BB;
    }
}

// ---------------------------------------------------------------------------
extern "C" void kernel_launch(void* const* d_in, const int* in_sizes, int n_in,
                              void* d_out, int out_size, void* d_ws, size_t ws_size,
                              hipStream_t stream) {
    (void)in_sizes; (void)n_in; (void)out_size; (void)ws_size;
    const int*   sub_x  = (const int*)d_in[0];
    const int*   edge   = (const int*)d_in[1];
    const int*   mapi   = (const int*)d_in[2];
    const int*   cand   = (const int*)d_in[3];
    const int*   fcand  = (const int*)d_in[4];
    const int*   label  = (const int*)d_in[5];
    const float* glove  = (const float*)d_in[6];
    const float* nwq    = (const float*)d_in[7];
    const float* nwk    = (const float*)d_in[8];
    const float* nwv    = (const float*)d_in[9];
    const float* nwp    = (const float*)d_in[10];
    const float* nqp    = (const float*)d_in[11];
    const float* ggc    = (const float*)d_in[12];
    const float* wih    = (const float*)d_in[13];
    const float* whh    = (const float*)d_in[14];
    const float* bih    = (const float*)d_in[15];
    const float* bhh    = (const float*)d_in[16];
    const float* wclick = (const float*)d_in[17];
    const float* bclick = (const float*)d_in[18];
    const float* uwq    = (const float*)d_in[19];
    const float* uwk    = (const float*)d_in[20];
    const float* uwv    = (const float*)d_in[21];
    const float* uwp    = (const float*)d_in[22];
    const float* uqp    = (const float*)d_in[23];

    // workspace layout (floats); ws_size = 256 MB
    float* ws     = (float*)d_ws;
    float* x_enc  = ws;                       // 4,000,000 f
    float* hbuf   = ws + 4000000;             // 4,000,000 f
    float* region = ws + 8000000;             // 8,000,000 f shared region
    unsigned short* mbufBF = (unsigned short*)region;   // GGC: m bf16 [NN][400]
    float* aggbuf = region + 4000000;         // GGC: agg f32
    // after GGC, region reused:
    float* ct   = region;                     // 1,280,000
    float* uq   = region + 1280000;
    float* uk   = region + 2560000;
    float* uv   = region + 3840000;
    float* uo   = region + 5120000;           // 1,280,000
    float* user = region + 6400000;           // 25,600
    float* crnc = region + 6425600;           // 128,000
    float* cfnc = region + 6553600;           // 128,000
    // int area at byte offset 64 MB
    int* ibase   = (int*)((char*)d_ws + (size_t)64*1024*1024);
    int* cnt     = ibase;                     // 10,000
    int* off     = ibase + 10000;             // 10,000
    int* cursor  = ibase + 20000;             // 10,000
    int* srclist = ibase + 30000;             // 200,000
    // bf16 prepped weights, beyond int area
    unsigned short* Wt   = (unsigned short*)(ws + 17100000);  // 1200*320 sh
    unsigned short* wpT  = (unsigned short*)(ws + 17300000);  // 208*416 sh
    unsigned short* wggT = (unsigned short*)(ws + 17400000);  // 3*400*424 sh
    unsigned short* wihT = (unsigned short*)(ws + 17700000);  // 1200*424 sh
    unsigned short* whhT = (unsigned short*)(ws + 18000000);  // 1200*424 sh

    // 0) prep transposed bf16 weights (tiny; L2-resident afterwards)
    prep_wt<<<1500, 256, 0, stream>>>(nwq, nwk, nwv, Wt);
    prep_wpt<<<338, 256, 0, stream>>>(nwp, wpT);
    prep_wgg<<<(3*400*424 + 255)/256, 256, 0, stream>>>(ggc, wggT);
    prep_gruw<<<(1200*424 + 255)/256, 256, 0, stream>>>(wih, whh, wihT, whhT);

    // 1) encode all nodes
    news_enc<<<NN, 256, 0, stream>>>(sub_x, TOKS, glove, Wt, wpT, nqp, x_enc);

    // 1b) build CSR-by-destination once (reused by all 3 GGC layers)
    hipMemsetAsync(cnt, 0, NN*sizeof(int), stream);
    count_edges<<<(EE+255)/256, 256, 0, stream>>>(edge, cnt);
    build_offsets<<<1, 256, 0, stream>>>(cnt, off, cursor);
    fill_csr<<<(EE+255)/256, 256, 0, stream>>>(edge, cursor, srclist);

    // 2) GatedGraphConv x3 (MFMA GEMMs + CSR gather)
    const float* hin = x_enc;
    const int nb32 = (NN + 31) / 32;   // 313
    for (int l = 0; l < 3; ++l) {
        mm_nodes_mfma<<<nb32, 256, 0, stream>>>(hin, wggT + (size_t)l*400*424, mbufBF);
        gather_agg<<<NN, 256, 0, stream>>>(mbufBF, off, cnt, srclist, aggbuf);
        gru_step_mfma<<<nb32, 256, 0, stream>>>(aggbuf, hin, wihT, whhT, bih, bhh, hbuf);
        hin = hbuf;
    }

    // 3) click + user encoder
    clicked_mm<<<(BB*NCK)/8, 256, 0, stream>>>(mapi, x_enc, hbuf, wclick, bclick, ct);
    user_qkv<<<(BB*NCK)/8, 256, 0, stream>>>(ct, uwq, uwk, uwv, uq, uk, uv);
    user_attn<<<BB*HH, 64, 0, stream>>>(uq, uk, uv, mapi, uo);
    user_pool<<<BB, 256, 0, stream>>>(uo, mapi, uwp, uqp, user);

    // 4) candidates
    news_enc<<<BB*NCAND, 256, 0, stream>>>(cand,  TOKS, glove, Wt, wpT, nqp, crnc);
    news_enc<<<BB*NCAND, 256, 0, stream>>>(fcand, TOKS, glove, Wt, wpT, nqp, cfnc);

    // 5) scores + loss
    score_loss<<<1, 256, 0, stream>>>(crnc, cfnc, user, label, (float*)d_out);
}